// Round 12
// baseline (167.857 us; speedup 1.0000x reference)
//
#include <hip/hip_runtime.h>
#include <hip/hip_bf16.h>
#include <math.h>

// Problem constants (from reference)
#define Dn 256     // feature dim
#define En 16      // hyperedges per node
#define Kn 3       // nodes per hyperedge
#define Hn 256     // hidden dim
#define Cn 40      // classes
#define CnP 48     // classes padded to 3x16 for MFMA col tiles

typedef __attribute__((ext_vector_type(8)))  short bf16x8;
typedef __attribute__((ext_vector_type(4)))  float f32x4;

static __device__ __forceinline__ float bf2f(unsigned short u) {
    return __uint_as_float(((unsigned)u) << 16);
}
static __device__ __forceinline__ unsigned short f2bfbits(float v) {
    __hip_bfloat16 hb = __float2bfloat16(v);
    return *reinterpret_cast<unsigned short*>(&hb);
}
static __device__ __forceinline__ unsigned pack2bf(float a, float b) {
    return (unsigned)f2bfbits(a) | ((unsigned)f2bfbits(b) << 16);
}
// 4-bit LDS swizzle for 16x512B tiles: XOR row (bits 9..12) into the 16B-slot
// index (bits 4..7). 16 distinct rows at a fixed slot-column -> 16 distinct
// slots -> conflict-free ds_read_b128 per 16-lane group.
static __device__ __forceinline__ unsigned swz4(unsigned boff) {
    return boff ^ (((boff >> 9) & 15u) << 4);
}

// ---------------------------------------------------------------------------
// Stage 0: merged fp32 -> bf16 conversion: X, lin_W, skip_W, cls_W (padded
// to 48 rows with zeros). One launch; each thread converts 8 floats.
// ---------------------------------------------------------------------------
__global__ __launch_bounds__(256) void conv_all(
    const float* __restrict__ X, const float* __restrict__ linW,
    const float* __restrict__ skipW, const float* __restrict__ clsW,
    uint4* __restrict__ Xb, uint4* __restrict__ linWb,
    uint4* __restrict__ skipWb, uint4* __restrict__ clsWb,
    int x8, int w8)
{
    int t = blockIdx.x * 256 + threadIdx.x;
    const int c8 = (CnP * Hn) / 8;
    if (t < x8) {
        const float4* iv = reinterpret_cast<const float4*>(X);
        const float4 a = iv[(size_t)t * 2 + 0];
        const float4 b = iv[(size_t)t * 2 + 1];
        Xb[t] = (uint4){pack2bf(a.x, a.y), pack2bf(a.z, a.w),
                        pack2bf(b.x, b.y), pack2bf(b.z, b.w)};
        return;
    }
    t -= x8;
    if (t < w8) {
        const float4* iv = reinterpret_cast<const float4*>(linW);
        const float4 a = iv[(size_t)t * 2 + 0];
        const float4 b = iv[(size_t)t * 2 + 1];
        linWb[t] = (uint4){pack2bf(a.x, a.y), pack2bf(a.z, a.w),
                           pack2bf(b.x, b.y), pack2bf(b.z, b.w)};
        return;
    }
    t -= w8;
    if (t < w8) {
        const float4* iv = reinterpret_cast<const float4*>(skipW);
        const float4 a = iv[(size_t)t * 2 + 0];
        const float4 b = iv[(size_t)t * 2 + 1];
        skipWb[t] = (uint4){pack2bf(a.x, a.y), pack2bf(a.z, a.w),
                            pack2bf(b.x, b.y), pack2bf(b.z, b.w)};
        return;
    }
    t -= w8;
    if (t < c8) {
        const int row = t >> 5;
        if (row < Cn) {
            const float4* iv = reinterpret_cast<const float4*>(clsW);
            const float4 a = iv[(size_t)t * 2 + 0];
            const float4 b = iv[(size_t)t * 2 + 1];
            clsWb[t] = (uint4){pack2bf(a.x, a.y), pack2bf(a.z, a.w),
                               pack2bf(b.x, b.y), pack2bf(b.z, b.w)};
        } else {
            clsWb[t] = (uint4){0u, 0u, 0u, 0u};
        }
    }
}

// ---------------------------------------------------------------------------
// Stage 1 (bf16): message passing. One wave per node b (5000 blocks x 4
// waves = 20000 waves -> proven 3.2-3.4 TB/s gather rate). Variance via
// S2-C identity. Streams self row out contiguously for the GEMM.
// ---------------------------------------------------------------------------
__global__ __launch_bounds__(256) void mp_kernel_bf(
    const int* __restrict__ nodes, const int* __restrict__ structure,
    const uint2* __restrict__ Xb,
    const float* __restrict__ waw_p, const float* __restrict__ wab_p,
    uint2* __restrict__ h_out, uint2* __restrict__ self_out, int B)
{
    const int wave = threadIdx.x >> 6;
    const int lane = threadIdx.x & 63;
    const int b = blockIdx.x * 4 + wave;
    if (b >= B) return;
    const int ub = __builtin_amdgcn_readfirstlane(b);  // wave-uniform

    const float waw = waw_p[0];
    const float wab = wab_p[0];

    float4 neigh = make_float4(0.f, 0.f, 0.f, 0.f);
    const int* st = structure + (size_t)ub * (En * Kn);

    #pragma unroll 1
    for (int g = 0; g < En / 4; ++g) {
        int idx[12];
        #pragma unroll
        for (int u = 0; u < 12; ++u) idx[u] = st[g * 12 + u];

        uint2 r0[4], r1[4], r2[4];
        #pragma unroll
        for (int u = 0; u < 4; ++u) {
            r0[u] = Xb[(size_t)idx[u * 3 + 0] * (Dn / 4) + lane];
            r1[u] = Xb[(size_t)idx[u * 3 + 1] * (Dn / 4) + lane];
            r2[u] = Xb[(size_t)idx[u * 3 + 2] * (Dn / 4) + lane];
        }

        float pv[4];
        float4 msg[4];
        #pragma unroll
        for (int u = 0; u < 4; ++u) {
            float4 f0, f1, f2;
            f0.x = bf2f((unsigned short)(r0[u].x & 0xffff));
            f0.y = bf2f((unsigned short)(r0[u].x >> 16));
            f0.z = bf2f((unsigned short)(r0[u].y & 0xffff));
            f0.w = bf2f((unsigned short)(r0[u].y >> 16));
            f1.x = bf2f((unsigned short)(r1[u].x & 0xffff));
            f1.y = bf2f((unsigned short)(r1[u].x >> 16));
            f1.z = bf2f((unsigned short)(r1[u].y & 0xffff));
            f1.w = bf2f((unsigned short)(r1[u].y >> 16));
            f2.x = bf2f((unsigned short)(r2[u].x & 0xffff));
            f2.y = bf2f((unsigned short)(r2[u].x >> 16));
            f2.z = bf2f((unsigned short)(r2[u].y & 0xffff));
            f2.w = bf2f((unsigned short)(r2[u].y >> 16));

            float s2 = 0.f, cr = 0.f, tt;
            s2 = fmaf(f0.x, f0.x, s2); s2 = fmaf(f1.x, f1.x, s2); s2 = fmaf(f2.x, f2.x, s2);
            tt = f1.x + f2.x; cr = fmaf(f0.x, tt, cr); cr = fmaf(f1.x, f2.x, cr);
            s2 = fmaf(f0.y, f0.y, s2); s2 = fmaf(f1.y, f1.y, s2); s2 = fmaf(f2.y, f2.y, s2);
            tt = f1.y + f2.y; cr = fmaf(f0.y, tt, cr); cr = fmaf(f1.y, f2.y, cr);
            s2 = fmaf(f0.z, f0.z, s2); s2 = fmaf(f1.z, f1.z, s2); s2 = fmaf(f2.z, f2.z, s2);
            tt = f1.z + f2.z; cr = fmaf(f0.z, tt, cr); cr = fmaf(f1.z, f2.z, cr);
            s2 = fmaf(f0.w, f0.w, s2); s2 = fmaf(f1.w, f1.w, s2); s2 = fmaf(f2.w, f2.w, s2);
            tt = f1.w + f2.w; cr = fmaf(f0.w, tt, cr); cr = fmaf(f1.w, f2.w, cr);

            pv[u] = s2 - cr;
            msg[u].x = f0.x * f1.x;
            msg[u].y = f0.y * f1.y;
            msg[u].z = f0.z * f1.z;
            msg[u].w = f0.w * f1.w;
        }

        #pragma unroll
        for (int off = 32; off; off >>= 1) {
            #pragma unroll
            for (int u = 0; u < 4; ++u) pv[u] += __shfl_xor(pv[u], off);
        }

        #pragma unroll
        for (int u = 0; u < 4; ++u) {
            const float var_mean = pv[u] * (2.f / (9.f * (float)Dn));
            const float att = 1.f / (1.f + expf(-(waw * var_mean + wab)));
            neigh.x += att * msg[u].x;
            neigh.y += att * msg[u].y;
            neigh.z += att * msg[u].z;
            neigh.w += att * msg[u].w;
        }
    }

    const uint2 sv = Xb[(size_t)nodes[ub] * (Dn / 4) + lane];
    self_out[(size_t)b * (Dn / 4) + lane] = sv;
    const float sx = bf2f((unsigned short)(sv.x & 0xffff));
    const float sy = bf2f((unsigned short)(sv.x >> 16));
    const float sz = bf2f((unsigned short)(sv.y & 0xffff));
    const float sw = bf2f((unsigned short)(sv.y >> 16));
    uint2 o;
    o.x = pack2bf(sx + neigh.x, sy + neigh.y);
    o.y = pack2bf(sz + neigh.z, sw + neigh.w);
    h_out[(size_t)b * (Dn / 4) + lane] = o;
}

// ---------------------------------------------------------------------------
// Stage 2+3 FUSED, high-occupancy: 16 rows/block -> 1250 blocks (=4.9/CU,
// ~19.5 waves/CU for latency hiding). 4 waves; wave w owns cols [w*64,+64)
// via 16x16x32 MFMA (4 col-tiles x 2 matrices, acc=32 VGPR). enc lands in
// 8KB swizzled LDS; wave 0 runs cls + log_softmax.
// 16x16 layouts (gfx950, verified): A row=lane&15, k=(lane>>4)*8+i;
// D col=lane&15, row=(lane>>4)*4+r.
// ---------------------------------------------------------------------------
__global__ __launch_bounds__(256, 8) void enc_cls16(
    const unsigned short* __restrict__ hB,     // [M,256] bf16
    const unsigned short* __restrict__ selfB,  // [M,256] bf16
    const unsigned short* __restrict__ linWb, const float* __restrict__ linb,
    const unsigned short* __restrict__ skipWb, const float* __restrict__ beta_p,
    const unsigned short* __restrict__ clsWb,  // [48,256] bf16 zero-padded
    const float* __restrict__ clsb,
    float* __restrict__ out, int M)
{
    __shared__ unsigned short elds[16 * 256];  // 8 KB, swizzled

    const int w    = threadIdx.x >> 6;   // col panel 0..3
    const int l    = threadIdx.x & 63;
    const int lr16 = l & 15;
    const int kg   = l >> 4;             // 0..3
    const int row0 = blockIdx.x * 16;

    const int arow = row0 + lr16;
    const int arc  = arow < M ? arow : (M - 1);

    f32x4 acc1[4], acc2[4];
    #pragma unroll
    for (int n = 0; n < 4; ++n) {
        acc1[n] = (f32x4){0.f, 0.f, 0.f, 0.f};
        acc2[n] = (f32x4){0.f, 0.f, 0.f, 0.f};
    }

    #pragma unroll 2
    for (int k0 = 0; k0 < Dn; k0 += 32) {
        const int ko = k0 + kg * 8;
        const bf16x8 a1 = *reinterpret_cast<const bf16x8*>(hB    + (size_t)arc * Dn + ko);
        const bf16x8 a2 = *reinterpret_cast<const bf16x8*>(selfB + (size_t)arc * Dn + ko);
        #pragma unroll
        for (int n = 0; n < 4; ++n) {
            const int col = w * 64 + n * 16 + lr16;
            const bf16x8 b1 = *reinterpret_cast<const bf16x8*>(linWb  + (size_t)col * Dn + ko);
            const bf16x8 b2 = *reinterpret_cast<const bf16x8*>(skipWb + (size_t)col * Dn + ko);
            acc1[n] = __builtin_amdgcn_mfma_f32_16x16x32_bf16(a1, b1, acc1[n], 0, 0, 0);
            acc2[n] = __builtin_amdgcn_mfma_f32_16x16x32_bf16(a2, b2, acc2[n], 0, 0, 0);
        }
    }

    // epilogue: enc -> swizzled LDS (bf16)
    const float beta = beta_p[0];
    const float omb = 1.f - beta;
    #pragma unroll
    for (int n = 0; n < 4; ++n) {
        const int col = w * 64 + n * 16 + lr16;
        const float bias = linb[col];
        #pragma unroll
        for (int r = 0; r < 4; ++r) {
            const int rowl = kg * 4 + r;          // 0..15
            const float c1 = fmaxf(acc1[n][r] + bias, 0.f);
            const unsigned short v = f2bfbits(omb * c1 + beta * acc2[n][r]);
            const unsigned boff = swz4((unsigned)(rowl * 512 + col * 2));
            *reinterpret_cast<unsigned short*>(
                reinterpret_cast<char*>(elds) + boff) = v;
        }
    }
    __syncthreads();

    // cls phase: wave 0 handles all 16 rows
    if (w == 0) {
        f32x4 cacc[3];
        cacc[0] = (f32x4){0.f,0.f,0.f,0.f};
        cacc[1] = (f32x4){0.f,0.f,0.f,0.f};
        cacc[2] = (f32x4){0.f,0.f,0.f,0.f};

        #pragma unroll
        for (int k0 = 0; k0 < Hn; k0 += 32) {
            const int ko = k0 + kg * 8;
            const unsigned boff = swz4((unsigned)(lr16 * 512 + ko * 2));
            const bf16x8 a = *reinterpret_cast<const bf16x8*>(
                reinterpret_cast<const char*>(elds) + boff);
            #pragma unroll
            for (int t = 0; t < 3; ++t) {
                const bf16x8 bb = *reinterpret_cast<const bf16x8*>(
                    clsWb + (size_t)(t * 16 + lr16) * Hn + ko);
                cacc[t] = __builtin_amdgcn_mfma_f32_16x16x32_bf16(a, bb, cacc[t], 0, 0, 0);
            }
        }

        float bias3[3];
        #pragma unroll
        for (int t = 0; t < 3; ++t) {
            const int cb = t * 16 + lr16;
            bias3[t] = (cb < Cn) ? clsb[cb] : -INFINITY;
        }

        #pragma unroll
        for (int r = 0; r < 4; ++r) {
            float lg0 = cacc[0][r] + bias3[0];
            float lg1 = cacc[1][r] + bias3[1];
            float lg2 = cacc[2][r] + bias3[2];
            float mx = fmaxf(fmaxf(lg0, lg1), lg2);
            #pragma unroll
            for (int off = 8; off; off >>= 1) mx = fmaxf(mx, __shfl_xor(mx, off));
            float se = expf(lg0 - mx) + expf(lg1 - mx) + expf(lg2 - mx);
            #pragma unroll
            for (int off = 8; off; off >>= 1) se += __shfl_xor(se, off);
            const float lse = logf(se);

            const int row = row0 + kg * 4 + r;
            if (row < M) {
                if (lr16 < 8) out[(size_t)row * Cn + 32 + lr16] = lg2 - mx - lse;
                out[(size_t)row * Cn + lr16]      = lg0 - mx - lse;
                out[(size_t)row * Cn + 16 + lr16] = lg1 - mx - lse;
            }
        }
    }
}

// ---------------------------------------------------------------------------
// fp32 fallback path (only if ws_size too small for bf16 copies)
// ---------------------------------------------------------------------------
__global__ __launch_bounds__(256) void mp_kernel_f32(
    const int* __restrict__ nodes, const int* __restrict__ structure,
    const float* __restrict__ X, const float* __restrict__ waw_p,
    const float* __restrict__ wab_p, float* __restrict__ h_out, int B)
{
    const int wave = threadIdx.x >> 6;
    const int lane = threadIdx.x & 63;
    const int b = blockIdx.x * 4 + wave;
    if (b >= B) return;
    const int ub = __builtin_amdgcn_readfirstlane(b);

    const float waw = waw_p[0];
    const float wab = wab_p[0];
    const float4* __restrict__ Xv = reinterpret_cast<const float4*>(X);

    float4 neigh = make_float4(0.f, 0.f, 0.f, 0.f);
    const int* st = structure + (size_t)ub * (En * Kn);

    #pragma unroll 1
    for (int e = 0; e < En; ++e) {
        const int i0 = st[e * 3 + 0];
        const int i1 = st[e * 3 + 1];
        const int i2 = st[e * 3 + 2];
        const float4 f0 = Xv[(size_t)i0 * (Dn / 4) + lane];
        const float4 f1 = Xv[(size_t)i1 * (Dn / 4) + lane];
        const float4 f2 = Xv[(size_t)i2 * (Dn / 4) + lane];
        float pv = 0.f;
        {
            float a, bb, c, m;
            a = f0.x; bb = f1.x; c = f2.x;
            m = (a + bb + c) * (1.f / 3.f);
            pv += (a * a + bb * bb + c * c) * (1.f / 3.f) - m * m;
            a = f0.y; bb = f1.y; c = f2.y;
            m = (a + bb + c) * (1.f / 3.f);
            pv += (a * a + bb * bb + c * c) * (1.f / 3.f) - m * m;
            a = f0.z; bb = f1.z; c = f2.z;
            m = (a + bb + c) * (1.f / 3.f);
            pv += (a * a + bb * bb + c * c) * (1.f / 3.f) - m * m;
            a = f0.w; bb = f1.w; c = f2.w;
            m = (a + bb + c) * (1.f / 3.f);
            pv += (a * a + bb * bb + c * c) * (1.f / 3.f) - m * m;
        }
        #pragma unroll
        for (int off = 32; off; off >>= 1) pv += __shfl_xor(pv, off);
        const float var_mean = pv * (1.f / (float)Dn);
        const float att = 1.f / (1.f + expf(-(waw * var_mean + wab)));
        neigh.x += att * f0.x * f1.x;
        neigh.y += att * f0.y * f1.y;
        neigh.z += att * f0.z * f1.z;
        neigh.w += att * f0.w * f1.w;
    }

    const float4 s = Xv[(size_t)nodes[ub] * (Dn / 4) + lane];
    float4 h;
    h.x = s.x + neigh.x; h.y = s.y + neigh.y;
    h.z = s.z + neigh.z; h.w = s.w + neigh.w;
    reinterpret_cast<float4*>(h_out)[(size_t)b * (Dn / 4) + lane] = h;
}

#define BM 64
#define BN 64
#define BKs 16
#define LDT 68

__global__ __launch_bounds__(256) void enc_gemm_f32(
    const float* __restrict__ hA, const int* __restrict__ nodes,
    const float* __restrict__ X,
    const float* __restrict__ linW, const float* __restrict__ linb,
    const float* __restrict__ skipW, const float* __restrict__ beta_p,
    float* __restrict__ enc2, int M)
{
    __shared__ float Ats1[BKs][LDT];
    __shared__ float Ats2[BKs][LDT];
    __shared__ float Bts1[BKs][LDT];
    __shared__ float Bts2[BKs][LDT];

    const int tid = threadIdx.x;
    const int tx = tid & 15;
    const int ty = tid >> 4;
    const int row0 = blockIdx.x * BM;
    const int col0 = blockIdx.y * BN;

    const int lr = tid >> 2;
    const int lc = tid & 3;

    const int arow = row0 + lr;
    const bool arow_ok = arow < M;
    const int self_row = arow_ok ? nodes[arow] : 0;

    float acc1[4][4] = {{0.f}}, acc2[4][4] = {{0.f}};

    for (int k0 = 0; k0 < Dn; k0 += BKs) {
        float4 a1v = make_float4(0.f, 0.f, 0.f, 0.f);
        float4 a2v = make_float4(0.f, 0.f, 0.f, 0.f);
        if (arow_ok) {
            a1v = *reinterpret_cast<const float4*>(hA + (size_t)arow * Dn + k0 + lc * 4);
            a2v = *reinterpret_cast<const float4*>(X + (size_t)self_row * Dn + k0 + lc * 4);
        }
        const float4 b1v = *reinterpret_cast<const float4*>(linW + (size_t)(col0 + lr) * Dn + k0 + lc * 4);
        const float4 b2v = *reinterpret_cast<const float4*>(skipW + (size_t)(col0 + lr) * Dn + k0 + lc * 4);

        __syncthreads();
        Ats1[lc * 4 + 0][lr] = a1v.x; Ats1[lc * 4 + 1][lr] = a1v.y;
        Ats1[lc * 4 + 2][lr] = a1v.z; Ats1[lc * 4 + 3][lr] = a1v.w;
        Ats2[lc * 4 + 0][lr] = a2v.x; Ats2[lc * 4 + 1][lr] = a2v.y;
        Ats2[lc * 4 + 2][lr] = a2v.z; Ats2[lc * 4 + 3][lr] = a2v.w;
        Bts1[lc * 4 + 0][lr] = b1v.x; Bts1[lc * 4 + 1][lr] = b1v.y;
        Bts1[lc * 4 + 2][lr] = b1v.z; Bts1[lc * 4 + 3][lr] = b1v.w;
        Bts2[lc * 4 + 0][lr] = b2v.x; Bts2[lc * 4 + 1][lr] = b2v.y;
        Bts2[lc * 4 + 2][lr] = b2v.z; Bts2[lc * 4 + 3][lr] = b2v.w;
        __syncthreads();

        #pragma unroll
        for (int kk = 0; kk < BKs; ++kk) {
            const float4 a1 = *reinterpret_cast<const float4*>(&Ats1[kk][ty * 4]);
            const float4 a2 = *reinterpret_cast<const float4*>(&Ats2[kk][ty * 4]);
            const float4 b1 = *reinterpret_cast<const float4*>(&Bts1[kk][tx * 4]);
            const float4 b2 = *reinterpret_cast<const float4*>(&Bts2[kk][tx * 4]);
            const float a1a[4] = {a1.x, a1.y, a1.z, a1.w};
            const float a2a[4] = {a2.x, a2.y, a2.z, a2.w};
            const float b1a[4] = {b1.x, b1.y, b1.z, b1.w};
            const float b2a[4] = {b2.x, b2.y, b2.z, b2.w};
            #pragma unroll
            for (int i = 0; i < 4; ++i)
                #pragma unroll
                for (int j = 0; j < 4; ++j) {
                    acc1[i][j] = fmaf(a1a[i], b1a[j], acc1[i][j]);
                    acc2[i][j] = fmaf(a2a[i], b2a[j], acc2[i][j]);
                }
        }
    }

    const float beta = beta_p[0];
    const float omb = 1.f - beta;
    #pragma unroll
    for (int i = 0; i < 4; ++i) {
        const int r = row0 + ty * 4 + i;
        if (r >= M) continue;
        #pragma unroll
        for (int j = 0; j < 4; ++j) {
            const int c = col0 + tx * 4 + j;
            float c1 = acc1[i][j] + linb[c];
            c1 = fmaxf(c1, 0.f);
            enc2[(size_t)r * Hn + c] = omb * c1 + beta * acc2[i][j];
        }
    }
}

__global__ __launch_bounds__(256) void cls_kernel_f32(
    const float* __restrict__ enc2, const float* __restrict__ clsW,
    const float* __restrict__ clsb, float* __restrict__ out, int B)
{
    const int wave = threadIdx.x >> 6;
    const int lane = threadIdx.x & 63;
    const int b = blockIdx.x * 4 + wave;
    if (b >= B) return;

    const float4 e = reinterpret_cast<const float4*>(enc2 + (size_t)b * Hn)[lane];
    const float4* __restrict__ clsWv = reinterpret_cast<const float4*>(clsW);

    float mylogit = -INFINITY;
    #pragma unroll
    for (int c0 = 0; c0 < Cn; c0 += 8) {
        float p[8];
        #pragma unroll
        for (int u = 0; u < 8; ++u) {
            const float4 wv = clsWv[(size_t)(c0 + u) * (Hn / 4) + lane];
            p[u] = e.x * wv.x + e.y * wv.y + e.z * wv.z + e.w * wv.w;
        }
        #pragma unroll
        for (int off = 32; off; off >>= 1) {
            #pragma unroll
            for (int u = 0; u < 8; ++u) p[u] += __shfl_xor(p[u], off);
        }
        #pragma unroll
        for (int u = 0; u < 8; ++u)
            if (lane == c0 + u) mylogit = p[u];
    }
    if (lane < Cn) mylogit += clsb[lane];

    float mx = mylogit;
    #pragma unroll
    for (int off = 32; off; off >>= 1) mx = fmaxf(mx, __shfl_xor(mx, off));
    float ex = (lane < Cn) ? expf(mylogit - mx) : 0.f;
    float se = ex;
    #pragma unroll
    for (int off = 32; off; off >>= 1) se += __shfl_xor(se, off);
    const float lse = logf(se);

    if (lane < Cn) out[(size_t)b * Cn + lane] = mylogit - mx - lse;
}

// ---------------------------------------------------------------------------
extern "C" void kernel_launch(void* const* d_in, const int* in_sizes, int n_in,
                              void* d_out, int out_size, void* d_ws, size_t ws_size,
                              hipStream_t stream) {
    const int*   nodes     = (const int*)d_in[0];
    const int*   structure = (const int*)d_in[1];
    const float* X         = (const float*)d_in[2];
    const float* beta      = (const float*)d_in[3];
    const float* waw       = (const float*)d_in[4];
    const float* wab       = (const float*)d_in[5];
    const float* linW      = (const float*)d_in[6];
    const float* linb      = (const float*)d_in[7];
    const float* skipW     = (const float*)d_in[8];
    const float* clsW      = (const float*)d_in[9];
    const float* clsb      = (const float*)d_in[10];
    float* out = (float*)d_out;

    const int B = in_sizes[0];
    const int Ntot = in_sizes[2];            // N * D floats

    // ws layout (bf16 path):
    //   h_bf   [B,D]   bf16
    //   selfb  [B,D]   bf16
    //   Xb     [N,D]   bf16
    //   linWb  [H,D]   bf16
    //   skipWb [H,D]   bf16
    //   clsWb  [48,H]  bf16 (zero-padded)
    unsigned short* h_bf   = (unsigned short*)d_ws;
    unsigned short* selfb  = h_bf + (size_t)B * Dn;
    unsigned short* Xb     = selfb + (size_t)B * Dn;
    unsigned short* linWb  = Xb + (size_t)Ntot;
    unsigned short* skipWb = linWb + (size_t)Hn * Dn;
    unsigned short* clsWb  = skipWb + (size_t)Hn * Dn;

    const size_t need = ((size_t)B * Dn * 2 + (size_t)Ntot +
                         (size_t)Hn * Dn * 2 + (size_t)CnP * Hn) * 2;

    if (ws_size >= need) {
        // Stage 0: one merged bf16 conversion launch
        const int x8 = Ntot / 8;
        const int w8 = (Hn * Dn) / 8;
        const int c8 = (CnP * Hn) / 8;
        const int G = x8 + 2 * w8 + c8;
        conv_all<<<(G + 255) / 256, 256, 0, stream>>>(
            X, linW, skipW, clsW,
            (uint4*)Xb, (uint4*)linWb, (uint4*)skipWb, (uint4*)clsWb, x8, w8);

        // Stage 1: message passing (bf16 gathers) -> h_bf, selfb
        mp_kernel_bf<<<(B + 3) / 4, 256, 0, stream>>>(
            nodes, structure, (const uint2*)Xb, waw, wab,
            (uint2*)h_bf, (uint2*)selfb, B);

        // Stage 2+3: fused dual-GEMM + classifier, 16 rows/block
        enc_cls16<<<(B + 15) / 16, 256, 0, stream>>>(
            h_bf, selfb, linWb, linb, skipWb, beta, clsWb, clsb, out, B);
    } else {
        float* enc2 = (float*)d_ws;
        float* hf   = enc2 + (size_t)B * Hn;
        mp_kernel_f32<<<(B + 3) / 4, 256, 0, stream>>>(nodes, structure, X, waw, wab, hf, B);
        dim3 g2((B + BM - 1) / BM, Hn / BN);
        enc_gemm_f32<<<g2, 256, 0, stream>>>(hf, nodes, X, linW, linb, skipW, beta, enc2, B);
        cls_kernel_f32<<<(B + 3) / 4, 256, 0, stream>>>(enc2, clsW, clsb, out, B);
    }
}

// Round 13
// 148.477 us; speedup vs baseline: 1.1305x; 1.1305x over previous
//
#include <hip/hip_runtime.h>
#include <hip/hip_bf16.h>
#include <math.h>

// Problem constants (from reference)
#define Dn 256     // feature dim
#define En 16      // hyperedges per node
#define Kn 3       // nodes per hyperedge
#define Hn 256     // hidden dim
#define Cn 40      // classes
#define CnP 48     // classes padded to 3x16 for MFMA col tiles

typedef __attribute__((ext_vector_type(8)))  short bf16x8;
typedef __attribute__((ext_vector_type(4)))  float f32x4;

static __device__ __forceinline__ float bf2f(unsigned short u) {
    return __uint_as_float(((unsigned)u) << 16);
}
static __device__ __forceinline__ unsigned short f2bfbits(float v) {
    __hip_bfloat16 hb = __float2bfloat16(v);
    return *reinterpret_cast<unsigned short*>(&hb);
}
static __device__ __forceinline__ unsigned pack2bf(float a, float b) {
    return (unsigned)f2bfbits(a) | ((unsigned)f2bfbits(b) << 16);
}
// 4-bit LDS swizzle for 16x512B tiles: XOR row (bits 9..12) into the 16B-slot
// index (bits 4..7). 16 distinct rows at a fixed slot-column -> 16 distinct
// slots -> conflict-free ds_read_b128 per 16-lane group.
static __device__ __forceinline__ unsigned swz4(unsigned boff) {
    return boff ^ (((boff >> 9) & 15u) << 4);
}

// ---------------------------------------------------------------------------
// Stage 0: merged fp32 -> bf16 conversion: X, lin_W, skip_W, cls_W (padded
// to 48 rows with zeros). One launch; each thread converts 8 floats.
// ---------------------------------------------------------------------------
__global__ __launch_bounds__(256) void conv_all(
    const float* __restrict__ X, const float* __restrict__ linW,
    const float* __restrict__ skipW, const float* __restrict__ clsW,
    uint4* __restrict__ Xb, uint4* __restrict__ linWb,
    uint4* __restrict__ skipWb, uint4* __restrict__ clsWb,
    int x8, int w8)
{
    int t = blockIdx.x * 256 + threadIdx.x;
    const int c8 = (CnP * Hn) / 8;
    if (t < x8) {
        const float4* iv = reinterpret_cast<const float4*>(X);
        const float4 a = iv[(size_t)t * 2 + 0];
        const float4 b = iv[(size_t)t * 2 + 1];
        Xb[t] = (uint4){pack2bf(a.x, a.y), pack2bf(a.z, a.w),
                        pack2bf(b.x, b.y), pack2bf(b.z, b.w)};
        return;
    }
    t -= x8;
    if (t < w8) {
        const float4* iv = reinterpret_cast<const float4*>(linW);
        const float4 a = iv[(size_t)t * 2 + 0];
        const float4 b = iv[(size_t)t * 2 + 1];
        linWb[t] = (uint4){pack2bf(a.x, a.y), pack2bf(a.z, a.w),
                           pack2bf(b.x, b.y), pack2bf(b.z, b.w)};
        return;
    }
    t -= w8;
    if (t < w8) {
        const float4* iv = reinterpret_cast<const float4*>(skipW);
        const float4 a = iv[(size_t)t * 2 + 0];
        const float4 b = iv[(size_t)t * 2 + 1];
        skipWb[t] = (uint4){pack2bf(a.x, a.y), pack2bf(a.z, a.w),
                            pack2bf(b.x, b.y), pack2bf(b.z, b.w)};
        return;
    }
    t -= w8;
    if (t < c8) {
        const int row = t >> 5;
        if (row < Cn) {
            const float4* iv = reinterpret_cast<const float4*>(clsW);
            const float4 a = iv[(size_t)t * 2 + 0];
            const float4 b = iv[(size_t)t * 2 + 1];
            clsWb[t] = (uint4){pack2bf(a.x, a.y), pack2bf(a.z, a.w),
                               pack2bf(b.x, b.y), pack2bf(b.z, b.w)};
        } else {
            clsWb[t] = (uint4){0u, 0u, 0u, 0u};
        }
    }
}

// ---------------------------------------------------------------------------
// Stage 1 (bf16): message passing. One wave per node b (5000 blocks x 4
// waves = 20000 waves -> proven 3.2-3.4 TB/s gather rate). Variance via
// S2-C identity. Streams self row out contiguously for the GEMM.
// ---------------------------------------------------------------------------
__global__ __launch_bounds__(256) void mp_kernel_bf(
    const int* __restrict__ nodes, const int* __restrict__ structure,
    const uint2* __restrict__ Xb,
    const float* __restrict__ waw_p, const float* __restrict__ wab_p,
    uint2* __restrict__ h_out, uint2* __restrict__ self_out, int B)
{
    const int wave = threadIdx.x >> 6;
    const int lane = threadIdx.x & 63;
    const int b = blockIdx.x * 4 + wave;
    if (b >= B) return;
    const int ub = __builtin_amdgcn_readfirstlane(b);  // wave-uniform

    const float waw = waw_p[0];
    const float wab = wab_p[0];

    float4 neigh = make_float4(0.f, 0.f, 0.f, 0.f);
    const int* st = structure + (size_t)ub * (En * Kn);

    #pragma unroll 1
    for (int g = 0; g < En / 4; ++g) {
        int idx[12];
        #pragma unroll
        for (int u = 0; u < 12; ++u) idx[u] = st[g * 12 + u];

        uint2 r0[4], r1[4], r2[4];
        #pragma unroll
        for (int u = 0; u < 4; ++u) {
            r0[u] = Xb[(size_t)idx[u * 3 + 0] * (Dn / 4) + lane];
            r1[u] = Xb[(size_t)idx[u * 3 + 1] * (Dn / 4) + lane];
            r2[u] = Xb[(size_t)idx[u * 3 + 2] * (Dn / 4) + lane];
        }

        float pv[4];
        float4 msg[4];
        #pragma unroll
        for (int u = 0; u < 4; ++u) {
            float4 f0, f1, f2;
            f0.x = bf2f((unsigned short)(r0[u].x & 0xffff));
            f0.y = bf2f((unsigned short)(r0[u].x >> 16));
            f0.z = bf2f((unsigned short)(r0[u].y & 0xffff));
            f0.w = bf2f((unsigned short)(r0[u].y >> 16));
            f1.x = bf2f((unsigned short)(r1[u].x & 0xffff));
            f1.y = bf2f((unsigned short)(r1[u].x >> 16));
            f1.z = bf2f((unsigned short)(r1[u].y & 0xffff));
            f1.w = bf2f((unsigned short)(r1[u].y >> 16));
            f2.x = bf2f((unsigned short)(r2[u].x & 0xffff));
            f2.y = bf2f((unsigned short)(r2[u].x >> 16));
            f2.z = bf2f((unsigned short)(r2[u].y & 0xffff));
            f2.w = bf2f((unsigned short)(r2[u].y >> 16));

            float s2 = 0.f, cr = 0.f, tt;
            s2 = fmaf(f0.x, f0.x, s2); s2 = fmaf(f1.x, f1.x, s2); s2 = fmaf(f2.x, f2.x, s2);
            tt = f1.x + f2.x; cr = fmaf(f0.x, tt, cr); cr = fmaf(f1.x, f2.x, cr);
            s2 = fmaf(f0.y, f0.y, s2); s2 = fmaf(f1.y, f1.y, s2); s2 = fmaf(f2.y, f2.y, s2);
            tt = f1.y + f2.y; cr = fmaf(f0.y, tt, cr); cr = fmaf(f1.y, f2.y, cr);
            s2 = fmaf(f0.z, f0.z, s2); s2 = fmaf(f1.z, f1.z, s2); s2 = fmaf(f2.z, f2.z, s2);
            tt = f1.z + f2.z; cr = fmaf(f0.z, tt, cr); cr = fmaf(f1.z, f2.z, cr);
            s2 = fmaf(f0.w, f0.w, s2); s2 = fmaf(f1.w, f1.w, s2); s2 = fmaf(f2.w, f2.w, s2);
            tt = f1.w + f2.w; cr = fmaf(f0.w, tt, cr); cr = fmaf(f1.w, f2.w, cr);

            pv[u] = s2 - cr;
            msg[u].x = f0.x * f1.x;
            msg[u].y = f0.y * f1.y;
            msg[u].z = f0.z * f1.z;
            msg[u].w = f0.w * f1.w;
        }

        #pragma unroll
        for (int off = 32; off; off >>= 1) {
            #pragma unroll
            for (int u = 0; u < 4; ++u) pv[u] += __shfl_xor(pv[u], off);
        }

        #pragma unroll
        for (int u = 0; u < 4; ++u) {
            const float var_mean = pv[u] * (2.f / (9.f * (float)Dn));
            const float att = 1.f / (1.f + expf(-(waw * var_mean + wab)));
            neigh.x += att * msg[u].x;
            neigh.y += att * msg[u].y;
            neigh.z += att * msg[u].z;
            neigh.w += att * msg[u].w;
        }
    }

    const uint2 sv = Xb[(size_t)nodes[ub] * (Dn / 4) + lane];
    self_out[(size_t)b * (Dn / 4) + lane] = sv;
    const float sx = bf2f((unsigned short)(sv.x & 0xffff));
    const float sy = bf2f((unsigned short)(sv.x >> 16));
    const float sz = bf2f((unsigned short)(sv.y & 0xffff));
    const float sw = bf2f((unsigned short)(sv.y >> 16));
    uint2 o;
    o.x = pack2bf(sx + neigh.x, sy + neigh.y);
    o.y = pack2bf(sz + neigh.z, sw + neigh.w);
    h_out[(size_t)b * (Dn / 4) + lane] = o;
}

// ---------------------------------------------------------------------------
// Stage 2+3 FUSED, high-occupancy: 16 rows/block -> 1250 blocks (=4.9/CU).
// 4 waves; wave w owns cols [w*64,+64) via 16x16x32 MFMA (4 col-tiles x 2
// matrices, acc=32 VGPR). enc lands in 8KB swizzled LDS; wave 0 runs cls.
// __launch_bounds__(256,4): VGPR cap 128 (v12's (256,8) capped at 64 ->
// massive scratch spill, WRITE_SIZE 120MB, 79us. 4 blocks/CU at 8KB LDS
// still = 16 waves/CU).
// ---------------------------------------------------------------------------
__global__ __launch_bounds__(256, 4) void enc_cls16(
    const unsigned short* __restrict__ hB,     // [M,256] bf16
    const unsigned short* __restrict__ selfB,  // [M,256] bf16
    const unsigned short* __restrict__ linWb, const float* __restrict__ linb,
    const unsigned short* __restrict__ skipWb, const float* __restrict__ beta_p,
    const unsigned short* __restrict__ clsWb,  // [48,256] bf16 zero-padded
    const float* __restrict__ clsb,
    float* __restrict__ out, int M)
{
    __shared__ unsigned short elds[16 * 256];  // 8 KB, swizzled

    const int w    = threadIdx.x >> 6;   // col panel 0..3
    const int l    = threadIdx.x & 63;
    const int lr16 = l & 15;
    const int kg   = l >> 4;             // 0..3
    const int row0 = blockIdx.x * 16;

    const int arow = row0 + lr16;
    const int arc  = arow < M ? arow : (M - 1);

    f32x4 acc1[4], acc2[4];
    #pragma unroll
    for (int n = 0; n < 4; ++n) {
        acc1[n] = (f32x4){0.f, 0.f, 0.f, 0.f};
        acc2[n] = (f32x4){0.f, 0.f, 0.f, 0.f};
    }

    #pragma unroll 2
    for (int k0 = 0; k0 < Dn; k0 += 32) {
        const int ko = k0 + kg * 8;
        const bf16x8 a1 = *reinterpret_cast<const bf16x8*>(hB    + (size_t)arc * Dn + ko);
        const bf16x8 a2 = *reinterpret_cast<const bf16x8*>(selfB + (size_t)arc * Dn + ko);
        #pragma unroll
        for (int n = 0; n < 4; ++n) {
            const int col = w * 64 + n * 16 + lr16;
            const bf16x8 b1 = *reinterpret_cast<const bf16x8*>(linWb  + (size_t)col * Dn + ko);
            const bf16x8 b2 = *reinterpret_cast<const bf16x8*>(skipWb + (size_t)col * Dn + ko);
            acc1[n] = __builtin_amdgcn_mfma_f32_16x16x32_bf16(a1, b1, acc1[n], 0, 0, 0);
            acc2[n] = __builtin_amdgcn_mfma_f32_16x16x32_bf16(a2, b2, acc2[n], 0, 0, 0);
        }
    }

    // epilogue: enc -> swizzled LDS (bf16)
    const float beta = beta_p[0];
    const float omb = 1.f - beta;
    #pragma unroll
    for (int n = 0; n < 4; ++n) {
        const int col = w * 64 + n * 16 + lr16;
        const float bias = linb[col];
        #pragma unroll
        for (int r = 0; r < 4; ++r) {
            const int rowl = kg * 4 + r;          // 0..15
            const float c1 = fmaxf(acc1[n][r] + bias, 0.f);
            const unsigned short v = f2bfbits(omb * c1 + beta * acc2[n][r]);
            const unsigned boff = swz4((unsigned)(rowl * 512 + col * 2));
            *reinterpret_cast<unsigned short*>(
                reinterpret_cast<char*>(elds) + boff) = v;
        }
    }
    __syncthreads();

    // cls phase: wave 0 handles all 16 rows
    if (w == 0) {
        f32x4 cacc[3];
        cacc[0] = (f32x4){0.f,0.f,0.f,0.f};
        cacc[1] = (f32x4){0.f,0.f,0.f,0.f};
        cacc[2] = (f32x4){0.f,0.f,0.f,0.f};

        #pragma unroll
        for (int k0 = 0; k0 < Hn; k0 += 32) {
            const int ko = k0 + kg * 8;
            const unsigned boff = swz4((unsigned)(lr16 * 512 + ko * 2));
            const bf16x8 a = *reinterpret_cast<const bf16x8*>(
                reinterpret_cast<const char*>(elds) + boff);
            #pragma unroll
            for (int t = 0; t < 3; ++t) {
                const bf16x8 bb = *reinterpret_cast<const bf16x8*>(
                    clsWb + (size_t)(t * 16 + lr16) * Hn + ko);
                cacc[t] = __builtin_amdgcn_mfma_f32_16x16x32_bf16(a, bb, cacc[t], 0, 0, 0);
            }
        }

        float bias3[3];
        #pragma unroll
        for (int t = 0; t < 3; ++t) {
            const int cb = t * 16 + lr16;
            bias3[t] = (cb < Cn) ? clsb[cb] : -INFINITY;
        }

        #pragma unroll
        for (int r = 0; r < 4; ++r) {
            float lg0 = cacc[0][r] + bias3[0];
            float lg1 = cacc[1][r] + bias3[1];
            float lg2 = cacc[2][r] + bias3[2];
            float mx = fmaxf(fmaxf(lg0, lg1), lg2);
            #pragma unroll
            for (int off = 8; off; off >>= 1) mx = fmaxf(mx, __shfl_xor(mx, off));
            float se = expf(lg0 - mx) + expf(lg1 - mx) + expf(lg2 - mx);
            #pragma unroll
            for (int off = 8; off; off >>= 1) se += __shfl_xor(se, off);
            const float lse = logf(se);

            const int row = row0 + kg * 4 + r;
            if (row < M) {
                if (lr16 < 8) out[(size_t)row * Cn + 32 + lr16] = lg2 - mx - lse;
                out[(size_t)row * Cn + lr16]      = lg0 - mx - lse;
                out[(size_t)row * Cn + 16 + lr16] = lg1 - mx - lse;
            }
        }
    }
}

// ---------------------------------------------------------------------------
// fp32 fallback path (only if ws_size too small for bf16 copies)
// ---------------------------------------------------------------------------
__global__ __launch_bounds__(256) void mp_kernel_f32(
    const int* __restrict__ nodes, const int* __restrict__ structure,
    const float* __restrict__ X, const float* __restrict__ waw_p,
    const float* __restrict__ wab_p, float* __restrict__ h_out, int B)
{
    const int wave = threadIdx.x >> 6;
    const int lane = threadIdx.x & 63;
    const int b = blockIdx.x * 4 + wave;
    if (b >= B) return;
    const int ub = __builtin_amdgcn_readfirstlane(b);

    const float waw = waw_p[0];
    const float wab = wab_p[0];
    const float4* __restrict__ Xv = reinterpret_cast<const float4*>(X);

    float4 neigh = make_float4(0.f, 0.f, 0.f, 0.f);
    const int* st = structure + (size_t)ub * (En * Kn);

    #pragma unroll 1
    for (int e = 0; e < En; ++e) {
        const int i0 = st[e * 3 + 0];
        const int i1 = st[e * 3 + 1];
        const int i2 = st[e * 3 + 2];
        const float4 f0 = Xv[(size_t)i0 * (Dn / 4) + lane];
        const float4 f1 = Xv[(size_t)i1 * (Dn / 4) + lane];
        const float4 f2 = Xv[(size_t)i2 * (Dn / 4) + lane];
        float pv = 0.f;
        {
            float a, bb, c, m;
            a = f0.x; bb = f1.x; c = f2.x;
            m = (a + bb + c) * (1.f / 3.f);
            pv += (a * a + bb * bb + c * c) * (1.f / 3.f) - m * m;
            a = f0.y; bb = f1.y; c = f2.y;
            m = (a + bb + c) * (1.f / 3.f);
            pv += (a * a + bb * bb + c * c) * (1.f / 3.f) - m * m;
            a = f0.z; bb = f1.z; c = f2.z;
            m = (a + bb + c) * (1.f / 3.f);
            pv += (a * a + bb * bb + c * c) * (1.f / 3.f) - m * m;
            a = f0.w; bb = f1.w; c = f2.w;
            m = (a + bb + c) * (1.f / 3.f);
            pv += (a * a + bb * bb + c * c) * (1.f / 3.f) - m * m;
        }
        #pragma unroll
        for (int off = 32; off; off >>= 1) pv += __shfl_xor(pv, off);
        const float var_mean = pv * (1.f / (float)Dn);
        const float att = 1.f / (1.f + expf(-(waw * var_mean + wab)));
        neigh.x += att * f0.x * f1.x;
        neigh.y += att * f0.y * f1.y;
        neigh.z += att * f0.z * f1.z;
        neigh.w += att * f0.w * f1.w;
    }

    const float4 s = Xv[(size_t)nodes[ub] * (Dn / 4) + lane];
    float4 h;
    h.x = s.x + neigh.x; h.y = s.y + neigh.y;
    h.z = s.z + neigh.z; h.w = s.w + neigh.w;
    reinterpret_cast<float4*>(h_out)[(size_t)b * (Dn / 4) + lane] = h;
}

#define BM 64
#define BN 64
#define BKs 16
#define LDT 68

__global__ __launch_bounds__(256) void enc_gemm_f32(
    const float* __restrict__ hA, const int* __restrict__ nodes,
    const float* __restrict__ X,
    const float* __restrict__ linW, const float* __restrict__ linb,
    const float* __restrict__ skipW, const float* __restrict__ beta_p,
    float* __restrict__ enc2, int M)
{
    __shared__ float Ats1[BKs][LDT];
    __shared__ float Ats2[BKs][LDT];
    __shared__ float Bts1[BKs][LDT];
    __shared__ float Bts2[BKs][LDT];

    const int tid = threadIdx.x;
    const int tx = tid & 15;
    const int ty = tid >> 4;
    const int row0 = blockIdx.x * BM;
    const int col0 = blockIdx.y * BN;

    const int lr = tid >> 2;
    const int lc = tid & 3;

    const int arow = row0 + lr;
    const bool arow_ok = arow < M;
    const int self_row = arow_ok ? nodes[arow] : 0;

    float acc1[4][4] = {{0.f}}, acc2[4][4] = {{0.f}};

    for (int k0 = 0; k0 < Dn; k0 += BKs) {
        float4 a1v = make_float4(0.f, 0.f, 0.f, 0.f);
        float4 a2v = make_float4(0.f, 0.f, 0.f, 0.f);
        if (arow_ok) {
            a1v = *reinterpret_cast<const float4*>(hA + (size_t)arow * Dn + k0 + lc * 4);
            a2v = *reinterpret_cast<const float4*>(X + (size_t)self_row * Dn + k0 + lc * 4);
        }
        const float4 b1v = *reinterpret_cast<const float4*>(linW + (size_t)(col0 + lr) * Dn + k0 + lc * 4);
        const float4 b2v = *reinterpret_cast<const float4*>(skipW + (size_t)(col0 + lr) * Dn + k0 + lc * 4);

        __syncthreads();
        Ats1[lc * 4 + 0][lr] = a1v.x; Ats1[lc * 4 + 1][lr] = a1v.y;
        Ats1[lc * 4 + 2][lr] = a1v.z; Ats1[lc * 4 + 3][lr] = a1v.w;
        Ats2[lc * 4 + 0][lr] = a2v.x; Ats2[lc * 4 + 1][lr] = a2v.y;
        Ats2[lc * 4 + 2][lr] = a2v.z; Ats2[lc * 4 + 3][lr] = a2v.w;
        Bts1[lc * 4 + 0][lr] = b1v.x; Bts1[lc * 4 + 1][lr] = b1v.y;
        Bts1[lc * 4 + 2][lr] = b1v.z; Bts1[lc * 4 + 3][lr] = b1v.w;
        Bts2[lc * 4 + 0][lr] = b2v.x; Bts2[lc * 4 + 1][lr] = b2v.y;
        Bts2[lc * 4 + 2][lr] = b2v.z; Bts2[lc * 4 + 3][lr] = b2v.w;
        __syncthreads();

        #pragma unroll
        for (int kk = 0; kk < BKs; ++kk) {
            const float4 a1 = *reinterpret_cast<const float4*>(&Ats1[kk][ty * 4]);
            const float4 a2 = *reinterpret_cast<const float4*>(&Ats2[kk][ty * 4]);
            const float4 b1 = *reinterpret_cast<const float4*>(&Bts1[kk][tx * 4]);
            const float4 b2 = *reinterpret_cast<const float4*>(&Bts2[kk][tx * 4]);
            const float a1a[4] = {a1.x, a1.y, a1.z, a1.w};
            const float a2a[4] = {a2.x, a2.y, a2.z, a2.w};
            const float b1a[4] = {b1.x, b1.y, b1.z, b1.w};
            const float b2a[4] = {b2.x, b2.y, b2.z, b2.w};
            #pragma unroll
            for (int i = 0; i < 4; ++i)
                #pragma unroll
                for (int j = 0; j < 4; ++j) {
                    acc1[i][j] = fmaf(a1a[i], b1a[j], acc1[i][j]);
                    acc2[i][j] = fmaf(a2a[i], b2a[j], acc2[i][j]);
                }
        }
    }

    const float beta = beta_p[0];
    const float omb = 1.f - beta;
    #pragma unroll
    for (int i = 0; i < 4; ++i) {
        const int r = row0 + ty * 4 + i;
        if (r >= M) continue;
        #pragma unroll
        for (int j = 0; j < 4; ++j) {
            const int c = col0 + tx * 4 + j;
            float c1 = acc1[i][j] + linb[c];
            c1 = fmaxf(c1, 0.f);
            enc2[(size_t)r * Hn + c] = omb * c1 + beta * acc2[i][j];
        }
    }
}

__global__ __launch_bounds__(256) void cls_kernel_f32(
    const float* __restrict__ enc2, const float* __restrict__ clsW,
    const float* __restrict__ clsb, float* __restrict__ out, int B)
{
    const int wave = threadIdx.x >> 6;
    const int lane = threadIdx.x & 63;
    const int b = blockIdx.x * 4 + wave;
    if (b >= B) return;

    const float4 e = reinterpret_cast<const float4*>(enc2 + (size_t)b * Hn)[lane];
    const float4* __restrict__ clsWv = reinterpret_cast<const float4*>(clsW);

    float mylogit = -INFINITY;
    #pragma unroll
    for (int c0 = 0; c0 < Cn; c0 += 8) {
        float p[8];
        #pragma unroll
        for (int u = 0; u < 8; ++u) {
            const float4 wv = clsWv[(size_t)(c0 + u) * (Hn / 4) + lane];
            p[u] = e.x * wv.x + e.y * wv.y + e.z * wv.z + e.w * wv.w;
        }
        #pragma unroll
        for (int off = 32; off; off >>= 1) {
            #pragma unroll
            for (int u = 0; u < 8; ++u) p[u] += __shfl_xor(p[u], off);
        }
        #pragma unroll
        for (int u = 0; u < 8; ++u)
            if (lane == c0 + u) mylogit = p[u];
    }
    if (lane < Cn) mylogit += clsb[lane];

    float mx = mylogit;
    #pragma unroll
    for (int off = 32; off; off >>= 1) mx = fmaxf(mx, __shfl_xor(mx, off));
    float ex = (lane < Cn) ? expf(mylogit - mx) : 0.f;
    float se = ex;
    #pragma unroll
    for (int off = 32; off; off >>= 1) se += __shfl_xor(se, off);
    const float lse = logf(se);

    if (lane < Cn) out[(size_t)b * Cn + lane] = mylogit - mx - lse;
}

// ---------------------------------------------------------------------------
extern "C" void kernel_launch(void* const* d_in, const int* in_sizes, int n_in,
                              void* d_out, int out_size, void* d_ws, size_t ws_size,
                              hipStream_t stream) {
    const int*   nodes     = (const int*)d_in[0];
    const int*   structure = (const int*)d_in[1];
    const float* X         = (const float*)d_in[2];
    const float* beta      = (const float*)d_in[3];
    const float* waw       = (const float*)d_in[4];
    const float* wab       = (const float*)d_in[5];
    const float* linW      = (const float*)d_in[6];
    const float* linb      = (const float*)d_in[7];
    const float* skipW     = (const float*)d_in[8];
    const float* clsW      = (const float*)d_in[9];
    const float* clsb      = (const float*)d_in[10];
    float* out = (float*)d_out;

    const int B = in_sizes[0];
    const int Ntot = in_sizes[2];            // N * D floats

    // ws layout (bf16 path):
    //   h_bf   [B,D]   bf16
    //   selfb  [B,D]   bf16
    //   Xb     [N,D]   bf16
    //   linWb  [H,D]   bf16
    //   skipWb [H,D]   bf16
    //   clsWb  [48,H]  bf16 (zero-padded)
    unsigned short* h_bf   = (unsigned short*)d_ws;
    unsigned short* selfb  = h_bf + (size_t)B * Dn;
    unsigned short* Xb     = selfb + (size_t)B * Dn;
    unsigned short* linWb  = Xb + (size_t)Ntot;
    unsigned short* skipWb = linWb + (size_t)Hn * Dn;
    unsigned short* clsWb  = skipWb + (size_t)Hn * Dn;

    const size_t need = ((size_t)B * Dn * 2 + (size_t)Ntot +
                         (size_t)Hn * Dn * 2 + (size_t)CnP * Hn) * 2;

    if (ws_size >= need) {
        // Stage 0: one merged bf16 conversion launch
        const int x8 = Ntot / 8;
        const int w8 = (Hn * Dn) / 8;
        const int c8 = (CnP * Hn) / 8;
        const int G = x8 + 2 * w8 + c8;
        conv_all<<<(G + 255) / 256, 256, 0, stream>>>(
            X, linW, skipW, clsW,
            (uint4*)Xb, (uint4*)linWb, (uint4*)skipWb, (uint4*)clsWb, x8, w8);

        // Stage 1: message passing (bf16 gathers) -> h_bf, selfb
        mp_kernel_bf<<<(B + 3) / 4, 256, 0, stream>>>(
            nodes, structure, (const uint2*)Xb, waw, wab,
            (uint2*)h_bf, (uint2*)selfb, B);

        // Stage 2+3: fused dual-GEMM + classifier, 16 rows/block
        enc_cls16<<<(B + 15) / 16, 256, 0, stream>>>(
            h_bf, selfb, linWb, linb, skipWb, beta, clsWb, clsb, out, B);
    } else {
        float* enc2 = (float*)d_ws;
        float* hf   = enc2 + (size_t)B * Hn;
        mp_kernel_f32<<<(B + 3) / 4, 256, 0, stream>>>(nodes, structure, X, waw, wab, hf, B);
        dim3 g2((B + BM - 1) / BM, Hn / BN);
        enc_gemm_f32<<<g2, 256, 0, stream>>>(hf, nodes, X, linW, linb, skipW, beta, enc2, B);
        cls_kernel_f32<<<(B + 3) / 4, 256, 0, stream>>>(enc2, clsW, clsb, out, B);
    }
}

// Round 14
// 128.745 us; speedup vs baseline: 1.3038x; 1.1533x over previous
//
#include <hip/hip_runtime.h>
#include <hip/hip_bf16.h>
#include <math.h>

// Problem constants (from reference)
#define Dn 256     // feature dim
#define En 16      // hyperedges per node
#define Kn 3       // nodes per hyperedge
#define Hn 256     // hidden dim
#define Cn 40      // classes
#define CnP 48     // classes padded to 3x16 for MFMA col tiles

typedef __attribute__((ext_vector_type(8)))  short bf16x8;
typedef __attribute__((ext_vector_type(4)))  float f32x4;

static __device__ __forceinline__ float bf2f(unsigned short u) {
    return __uint_as_float(((unsigned)u) << 16);
}
static __device__ __forceinline__ unsigned short f2bfbits(float v) {
    __hip_bfloat16 hb = __float2bfloat16(v);
    return *reinterpret_cast<unsigned short*>(&hb);
}
static __device__ __forceinline__ unsigned pack2bf(float a, float b) {
    return (unsigned)f2bfbits(a) | ((unsigned)f2bfbits(b) << 16);
}
// 4-bit LDS swizzle for 16x512B tiles: XOR row (bits 9..12) into the 16B-slot
// index (bits 4..7). 16 distinct rows at a fixed slot-column -> 16 distinct
// slots -> conflict-free ds_read_b128 per 16-lane group.
static __device__ __forceinline__ unsigned swz4(unsigned boff) {
    return boff ^ (((boff >> 9) & 15u) << 4);
}

// ---------------------------------------------------------------------------
// Stage 0: merged fp32 -> bf16 conversion. X stays row-major; lin_W, skip_W,
// cls_W (zero-padded to 48 rows) are packed into MFMA-FRAGMENT ORDER:
//   packed[((ct*8 + kt)*64 + lane)] = 16B fragment (8 bf16) for
//   col = ct*16 + (lane&15), k = kt*32 + (lane>>4)*8 .. +7
// so a wave's B-fragment load is lane-consecutive (fully coalesced 1KB).
// Each thread converts 8 consecutive floats = exactly one fragment.
// ---------------------------------------------------------------------------
__global__ __launch_bounds__(256) void conv_all(
    const float* __restrict__ X, const float* __restrict__ linW,
    const float* __restrict__ skipW, const float* __restrict__ clsW,
    uint4* __restrict__ Xb, uint4* __restrict__ linWp,
    uint4* __restrict__ skipWp, uint4* __restrict__ clsWp,
    int x8, int w8)
{
    int t = blockIdx.x * 256 + threadIdx.x;
    const int c8 = (CnP * Hn) / 8;   // 1536 fragments for cls (48x256)
    if (t < x8) {
        const float4* iv = reinterpret_cast<const float4*>(X);
        const float4 a = iv[(size_t)t * 2 + 0];
        const float4 b = iv[(size_t)t * 2 + 1];
        Xb[t] = (uint4){pack2bf(a.x, a.y), pack2bf(a.z, a.w),
                        pack2bf(b.x, b.y), pack2bf(b.z, b.w)};
        return;
    }
    t -= x8;
    if (t < w8) {
        // thread t: col = t>>5, k = (t&31)*8 .. +7
        const float4* iv = reinterpret_cast<const float4*>(linW);
        const float4 a = iv[(size_t)t * 2 + 0];
        const float4 b = iv[(size_t)t * 2 + 1];
        const int lc = (t >> 5) & 15, ct = t >> 9;
        const int kt = (t >> 2) & 7,  kg = t & 3;
        linWp[(ct * 8 + kt) * 64 + kg * 16 + lc] =
            (uint4){pack2bf(a.x, a.y), pack2bf(a.z, a.w),
                    pack2bf(b.x, b.y), pack2bf(b.z, b.w)};
        return;
    }
    t -= w8;
    if (t < w8) {
        const float4* iv = reinterpret_cast<const float4*>(skipW);
        const float4 a = iv[(size_t)t * 2 + 0];
        const float4 b = iv[(size_t)t * 2 + 1];
        const int lc = (t >> 5) & 15, ct = t >> 9;
        const int kt = (t >> 2) & 7,  kg = t & 3;
        skipWp[(ct * 8 + kt) * 64 + kg * 16 + lc] =
            (uint4){pack2bf(a.x, a.y), pack2bf(a.z, a.w),
                    pack2bf(b.x, b.y), pack2bf(b.z, b.w)};
        return;
    }
    t -= w8;
    if (t < c8) {
        const int col = t >> 5;
        const int lc = col & 15, ct = t >> 9;
        const int kt = (t >> 2) & 7, kg = t & 3;
        const int dst = (ct * 8 + kt) * 64 + kg * 16 + lc;
        if (col < Cn) {
            const float4* iv = reinterpret_cast<const float4*>(clsW);
            const float4 a = iv[(size_t)t * 2 + 0];
            const float4 b = iv[(size_t)t * 2 + 1];
            clsWp[dst] = (uint4){pack2bf(a.x, a.y), pack2bf(a.z, a.w),
                                 pack2bf(b.x, b.y), pack2bf(b.z, b.w)};
        } else {
            clsWp[dst] = (uint4){0u, 0u, 0u, 0u};
        }
    }
}

// ---------------------------------------------------------------------------
// Stage 1 (bf16): message passing. One wave per node b (5000 blocks x 4
// waves = 20000 waves -> proven 3.2-3.4 TB/s gather rate). Variance via
// S2-C identity. Streams self row out contiguously for the GEMM.
// ---------------------------------------------------------------------------
__global__ __launch_bounds__(256) void mp_kernel_bf(
    const int* __restrict__ nodes, const int* __restrict__ structure,
    const uint2* __restrict__ Xb,
    const float* __restrict__ waw_p, const float* __restrict__ wab_p,
    uint2* __restrict__ h_out, uint2* __restrict__ self_out, int B)
{
    const int wave = threadIdx.x >> 6;
    const int lane = threadIdx.x & 63;
    const int b = blockIdx.x * 4 + wave;
    if (b >= B) return;
    const int ub = __builtin_amdgcn_readfirstlane(b);  // wave-uniform

    const float waw = waw_p[0];
    const float wab = wab_p[0];

    float4 neigh = make_float4(0.f, 0.f, 0.f, 0.f);
    const int* st = structure + (size_t)ub * (En * Kn);

    #pragma unroll 1
    for (int g = 0; g < En / 4; ++g) {
        int idx[12];
        #pragma unroll
        for (int u = 0; u < 12; ++u) idx[u] = st[g * 12 + u];

        uint2 r0[4], r1[4], r2[4];
        #pragma unroll
        for (int u = 0; u < 4; ++u) {
            r0[u] = Xb[(size_t)idx[u * 3 + 0] * (Dn / 4) + lane];
            r1[u] = Xb[(size_t)idx[u * 3 + 1] * (Dn / 4) + lane];
            r2[u] = Xb[(size_t)idx[u * 3 + 2] * (Dn / 4) + lane];
        }

        float pv[4];
        float4 msg[4];
        #pragma unroll
        for (int u = 0; u < 4; ++u) {
            float4 f0, f1, f2;
            f0.x = bf2f((unsigned short)(r0[u].x & 0xffff));
            f0.y = bf2f((unsigned short)(r0[u].x >> 16));
            f0.z = bf2f((unsigned short)(r0[u].y & 0xffff));
            f0.w = bf2f((unsigned short)(r0[u].y >> 16));
            f1.x = bf2f((unsigned short)(r1[u].x & 0xffff));
            f1.y = bf2f((unsigned short)(r1[u].x >> 16));
            f1.z = bf2f((unsigned short)(r1[u].y & 0xffff));
            f1.w = bf2f((unsigned short)(r1[u].y >> 16));
            f2.x = bf2f((unsigned short)(r2[u].x & 0xffff));
            f2.y = bf2f((unsigned short)(r2[u].x >> 16));
            f2.z = bf2f((unsigned short)(r2[u].y & 0xffff));
            f2.w = bf2f((unsigned short)(r2[u].y >> 16));

            float s2 = 0.f, cr = 0.f, tt;
            s2 = fmaf(f0.x, f0.x, s2); s2 = fmaf(f1.x, f1.x, s2); s2 = fmaf(f2.x, f2.x, s2);
            tt = f1.x + f2.x; cr = fmaf(f0.x, tt, cr); cr = fmaf(f1.x, f2.x, cr);
            s2 = fmaf(f0.y, f0.y, s2); s2 = fmaf(f1.y, f1.y, s2); s2 = fmaf(f2.y, f2.y, s2);
            tt = f1.y + f2.y; cr = fmaf(f0.y, tt, cr); cr = fmaf(f1.y, f2.y, cr);
            s2 = fmaf(f0.z, f0.z, s2); s2 = fmaf(f1.z, f1.z, s2); s2 = fmaf(f2.z, f2.z, s2);
            tt = f1.z + f2.z; cr = fmaf(f0.z, tt, cr); cr = fmaf(f1.z, f2.z, cr);
            s2 = fmaf(f0.w, f0.w, s2); s2 = fmaf(f1.w, f1.w, s2); s2 = fmaf(f2.w, f2.w, s2);
            tt = f1.w + f2.w; cr = fmaf(f0.w, tt, cr); cr = fmaf(f1.w, f2.w, cr);

            pv[u] = s2 - cr;
            msg[u].x = f0.x * f1.x;
            msg[u].y = f0.y * f1.y;
            msg[u].z = f0.z * f1.z;
            msg[u].w = f0.w * f1.w;
        }

        #pragma unroll
        for (int off = 32; off; off >>= 1) {
            #pragma unroll
            for (int u = 0; u < 4; ++u) pv[u] += __shfl_xor(pv[u], off);
        }

        #pragma unroll
        for (int u = 0; u < 4; ++u) {
            const float var_mean = pv[u] * (2.f / (9.f * (float)Dn));
            const float att = 1.f / (1.f + expf(-(waw * var_mean + wab)));
            neigh.x += att * msg[u].x;
            neigh.y += att * msg[u].y;
            neigh.z += att * msg[u].z;
            neigh.w += att * msg[u].w;
        }
    }

    const uint2 sv = Xb[(size_t)nodes[ub] * (Dn / 4) + lane];
    self_out[(size_t)b * (Dn / 4) + lane] = sv;
    const float sx = bf2f((unsigned short)(sv.x & 0xffff));
    const float sy = bf2f((unsigned short)(sv.x >> 16));
    const float sz = bf2f((unsigned short)(sv.y & 0xffff));
    const float sw = bf2f((unsigned short)(sv.y >> 16));
    uint2 o;
    o.x = pack2bf(sx + neigh.x, sy + neigh.y);
    o.y = pack2bf(sz + neigh.z, sw + neigh.w);
    h_out[(size_t)b * (Dn / 4) + lane] = o;
}

// ---------------------------------------------------------------------------
// Stage 2+3 FUSED v2, all fragment loads coalesced:
//  - h/self rows (16 each) staged to swizzled LDS via coalesced row loads;
//    A-fragments read conflict-free with ds_read_b128.
//  - B-fragments from fragment-packed weights: lane-consecutive 16B loads.
// 16 rows/block -> 1250 blocks; 4 waves (wave w = cols [w*64,+64));
// (256,4): VGPR cap 128 (no spill). enc -> elds; wave 0 runs cls.
// ---------------------------------------------------------------------------
__global__ __launch_bounds__(256, 4) void enc_cls16(
    const unsigned short* __restrict__ hB,     // [M,256] bf16
    const unsigned short* __restrict__ selfB,  // [M,256] bf16
    const uint4* __restrict__ linWp, const float* __restrict__ linb,
    const uint4* __restrict__ skipWp, const float* __restrict__ beta_p,
    const uint4* __restrict__ clsWp,           // packed [3][8][64]
    const float* __restrict__ clsb,
    float* __restrict__ out, int M)
{
    __shared__ unsigned short hlds[16 * 256];  // 8 KB swizzled
    __shared__ unsigned short slds[16 * 256];  // 8 KB swizzled
    __shared__ unsigned short elds[16 * 256];  // 8 KB swizzled (enc out)

    const int w    = threadIdx.x >> 6;   // col panel 0..3
    const int l    = threadIdx.x & 63;
    const int lr16 = l & 15;
    const int kg   = l >> 4;             // 0..3
    const int row0 = blockIdx.x * 16;

    // ---- stage h/self 16 rows each, coalesced -> swizzled LDS ----
    #pragma unroll
    for (int it = 0; it < 2; ++it) {
        const int ch = it * 256 + threadIdx.x;    // 0..511 (16B chunks)
        const int r  = ch >> 5;                   // 0..15
        const int c  = ch & 31;                   // 16B col within row
        int grow = row0 + r;
        grow = grow < M ? grow : (M - 1);
        const uint4 hv = *reinterpret_cast<const uint4*>(hB    + (size_t)grow * Dn + c * 8);
        const uint4 sv = *reinterpret_cast<const uint4*>(selfB + (size_t)grow * Dn + c * 8);
        const unsigned boff = swz4((unsigned)(r * 512 + c * 16));
        *reinterpret_cast<uint4*>(reinterpret_cast<char*>(hlds) + boff) = hv;
        *reinterpret_cast<uint4*>(reinterpret_cast<char*>(slds) + boff) = sv;
    }
    __syncthreads();

    f32x4 acc1[4], acc2[4];
    #pragma unroll
    for (int n = 0; n < 4; ++n) {
        acc1[n] = (f32x4){0.f, 0.f, 0.f, 0.f};
        acc2[n] = (f32x4){0.f, 0.f, 0.f, 0.f};
    }

    #pragma unroll 2
    for (int k0 = 0; k0 < Dn; k0 += 32) {
        const int kt = k0 >> 5;
        const unsigned aoff = swz4((unsigned)(lr16 * 512 + k0 * 2 + kg * 16));
        const bf16x8 a1 = *reinterpret_cast<const bf16x8*>(
            reinterpret_cast<const char*>(hlds) + aoff);
        const bf16x8 a2 = *reinterpret_cast<const bf16x8*>(
            reinterpret_cast<const char*>(slds) + aoff);
        #pragma unroll
        for (int n = 0; n < 4; ++n) {
            const int fidx = ((w * 4 + n) * 8 + kt) * 64 + l;   // coalesced
            const bf16x8 b1 = *reinterpret_cast<const bf16x8*>(linWp  + fidx);
            const bf16x8 b2 = *reinterpret_cast<const bf16x8*>(skipWp + fidx);
            acc1[n] = __builtin_amdgcn_mfma_f32_16x16x32_bf16(a1, b1, acc1[n], 0, 0, 0);
            acc2[n] = __builtin_amdgcn_mfma_f32_16x16x32_bf16(a2, b2, acc2[n], 0, 0, 0);
        }
    }

    // epilogue: enc -> elds (swizzled bf16)
    const float beta = beta_p[0];
    const float omb = 1.f - beta;
    #pragma unroll
    for (int n = 0; n < 4; ++n) {
        const int col = w * 64 + n * 16 + lr16;
        const float bias = linb[col];
        #pragma unroll
        for (int r = 0; r < 4; ++r) {
            const int rowl = kg * 4 + r;          // 0..15
            const float c1 = fmaxf(acc1[n][r] + bias, 0.f);
            const unsigned short v = f2bfbits(omb * c1 + beta * acc2[n][r]);
            const unsigned boff = swz4((unsigned)(rowl * 512 + col * 2));
            *reinterpret_cast<unsigned short*>(
                reinterpret_cast<char*>(elds) + boff) = v;
        }
    }
    __syncthreads();

    // cls phase: wave 0 handles all 16 rows (B from packed clsWp, coalesced)
    if (w == 0) {
        f32x4 cacc[3];
        cacc[0] = (f32x4){0.f,0.f,0.f,0.f};
        cacc[1] = (f32x4){0.f,0.f,0.f,0.f};
        cacc[2] = (f32x4){0.f,0.f,0.f,0.f};

        #pragma unroll
        for (int k0 = 0; k0 < Hn; k0 += 32) {
            const int kt = k0 >> 5;
            const unsigned boff = swz4((unsigned)(lr16 * 512 + k0 * 2 + kg * 16));
            const bf16x8 a = *reinterpret_cast<const bf16x8*>(
                reinterpret_cast<const char*>(elds) + boff);
            #pragma unroll
            for (int t = 0; t < 3; ++t) {
                const bf16x8 bb = *reinterpret_cast<const bf16x8*>(
                    clsWp + ((t * 8 + kt) * 64 + l));
                cacc[t] = __builtin_amdgcn_mfma_f32_16x16x32_bf16(a, bb, cacc[t], 0, 0, 0);
            }
        }

        float bias3[3];
        #pragma unroll
        for (int t = 0; t < 3; ++t) {
            const int cb = t * 16 + lr16;
            bias3[t] = (cb < Cn) ? clsb[cb] : -INFINITY;
        }

        #pragma unroll
        for (int r = 0; r < 4; ++r) {
            float lg0 = cacc[0][r] + bias3[0];
            float lg1 = cacc[1][r] + bias3[1];
            float lg2 = cacc[2][r] + bias3[2];
            float mx = fmaxf(fmaxf(lg0, lg1), lg2);
            #pragma unroll
            for (int off = 8; off; off >>= 1) mx = fmaxf(mx, __shfl_xor(mx, off));
            float se = expf(lg0 - mx) + expf(lg1 - mx) + expf(lg2 - mx);
            #pragma unroll
            for (int off = 8; off; off >>= 1) se += __shfl_xor(se, off);
            const float lse = logf(se);

            const int row = row0 + kg * 4 + r;
            if (row < M) {
                if (lr16 < 8) out[(size_t)row * Cn + 32 + lr16] = lg2 - mx - lse;
                out[(size_t)row * Cn + lr16]      = lg0 - mx - lse;
                out[(size_t)row * Cn + 16 + lr16] = lg1 - mx - lse;
            }
        }
    }
}

// ---------------------------------------------------------------------------
// fp32 fallback path (only if ws_size too small for bf16 copies)
// ---------------------------------------------------------------------------
__global__ __launch_bounds__(256) void mp_kernel_f32(
    const int* __restrict__ nodes, const int* __restrict__ structure,
    const float* __restrict__ X, const float* __restrict__ waw_p,
    const float* __restrict__ wab_p, float* __restrict__ h_out, int B)
{
    const int wave = threadIdx.x >> 6;
    const int lane = threadIdx.x & 63;
    const int b = blockIdx.x * 4 + wave;
    if (b >= B) return;
    const int ub = __builtin_amdgcn_readfirstlane(b);

    const float waw = waw_p[0];
    const float wab = wab_p[0];
    const float4* __restrict__ Xv = reinterpret_cast<const float4*>(X);

    float4 neigh = make_float4(0.f, 0.f, 0.f, 0.f);
    const int* st = structure + (size_t)ub * (En * Kn);

    #pragma unroll 1
    for (int e = 0; e < En; ++e) {
        const int i0 = st[e * 3 + 0];
        const int i1 = st[e * 3 + 1];
        const int i2 = st[e * 3 + 2];
        const float4 f0 = Xv[(size_t)i0 * (Dn / 4) + lane];
        const float4 f1 = Xv[(size_t)i1 * (Dn / 4) + lane];
        const float4 f2 = Xv[(size_t)i2 * (Dn / 4) + lane];
        float pv = 0.f;
        {
            float a, bb, c, m;
            a = f0.x; bb = f1.x; c = f2.x;
            m = (a + bb + c) * (1.f / 3.f);
            pv += (a * a + bb * bb + c * c) * (1.f / 3.f) - m * m;
            a = f0.y; bb = f1.y; c = f2.y;
            m = (a + bb + c) * (1.f / 3.f);
            pv += (a * a + bb * bb + c * c) * (1.f / 3.f) - m * m;
            a = f0.z; bb = f1.z; c = f2.z;
            m = (a + bb + c) * (1.f / 3.f);
            pv += (a * a + bb * bb + c * c) * (1.f / 3.f) - m * m;
            a = f0.w; bb = f1.w; c = f2.w;
            m = (a + bb + c) * (1.f / 3.f);
            pv += (a * a + bb * bb + c * c) * (1.f / 3.f) - m * m;
        }
        #pragma unroll
        for (int off = 32; off; off >>= 1) pv += __shfl_xor(pv, off);
        const float var_mean = pv * (1.f / (float)Dn);
        const float att = 1.f / (1.f + expf(-(waw * var_mean + wab)));
        neigh.x += att * f0.x * f1.x;
        neigh.y += att * f0.y * f1.y;
        neigh.z += att * f0.z * f1.z;
        neigh.w += att * f0.w * f1.w;
    }

    const float4 s = Xv[(size_t)nodes[ub] * (Dn / 4) + lane];
    float4 h;
    h.x = s.x + neigh.x; h.y = s.y + neigh.y;
    h.z = s.z + neigh.z; h.w = s.w + neigh.w;
    reinterpret_cast<float4*>(h_out)[(size_t)b * (Dn / 4) + lane] = h;
}

#define BM 64
#define BN 64
#define BKs 16
#define LDT 68

__global__ __launch_bounds__(256) void enc_gemm_f32(
    const float* __restrict__ hA, const int* __restrict__ nodes,
    const float* __restrict__ X,
    const float* __restrict__ linW, const float* __restrict__ linb,
    const float* __restrict__ skipW, const float* __restrict__ beta_p,
    float* __restrict__ enc2, int M)
{
    __shared__ float Ats1[BKs][LDT];
    __shared__ float Ats2[BKs][LDT];
    __shared__ float Bts1[BKs][LDT];
    __shared__ float Bts2[BKs][LDT];

    const int tid = threadIdx.x;
    const int tx = tid & 15;
    const int ty = tid >> 4;
    const int row0 = blockIdx.x * BM;
    const int col0 = blockIdx.y * BN;

    const int lr = tid >> 2;
    const int lc = tid & 3;

    const int arow = row0 + lr;
    const bool arow_ok = arow < M;
    const int self_row = arow_ok ? nodes[arow] : 0;

    float acc1[4][4] = {{0.f}}, acc2[4][4] = {{0.f}};

    for (int k0 = 0; k0 < Dn; k0 += BKs) {
        float4 a1v = make_float4(0.f, 0.f, 0.f, 0.f);
        float4 a2v = make_float4(0.f, 0.f, 0.f, 0.f);
        if (arow_ok) {
            a1v = *reinterpret_cast<const float4*>(hA + (size_t)arow * Dn + k0 + lc * 4);
            a2v = *reinterpret_cast<const float4*>(X + (size_t)self_row * Dn + k0 + lc * 4);
        }
        const float4 b1v = *reinterpret_cast<const float4*>(linW + (size_t)(col0 + lr) * Dn + k0 + lc * 4);
        const float4 b2v = *reinterpret_cast<const float4*>(skipW + (size_t)(col0 + lr) * Dn + k0 + lc * 4);

        __syncthreads();
        Ats1[lc * 4 + 0][lr] = a1v.x; Ats1[lc * 4 + 1][lr] = a1v.y;
        Ats1[lc * 4 + 2][lr] = a1v.z; Ats1[lc * 4 + 3][lr] = a1v.w;
        Ats2[lc * 4 + 0][lr] = a2v.x; Ats2[lc * 4 + 1][lr] = a2v.y;
        Ats2[lc * 4 + 2][lr] = a2v.z; Ats2[lc * 4 + 3][lr] = a2v.w;
        Bts1[lc * 4 + 0][lr] = b1v.x; Bts1[lc * 4 + 1][lr] = b1v.y;
        Bts1[lc * 4 + 2][lr] = b1v.z; Bts1[lc * 4 + 3][lr] = b1v.w;
        Bts2[lc * 4 + 0][lr] = b2v.x; Bts2[lc * 4 + 1][lr] = b2v.y;
        Bts2[lc * 4 + 2][lr] = b2v.z; Bts2[lc * 4 + 3][lr] = b2v.w;
        __syncthreads();

        #pragma unroll
        for (int kk = 0; kk < BKs; ++kk) {
            const float4 a1 = *reinterpret_cast<const float4*>(&Ats1[kk][ty * 4]);
            const float4 a2 = *reinterpret_cast<const float4*>(&Ats2[kk][ty * 4]);
            const float4 b1 = *reinterpret_cast<const float4*>(&Bts1[kk][tx * 4]);
            const float4 b2 = *reinterpret_cast<const float4*>(&Bts2[kk][tx * 4]);
            const float a1a[4] = {a1.x, a1.y, a1.z, a1.w};
            const float a2a[4] = {a2.x, a2.y, a2.z, a2.w};
            const float b1a[4] = {b1.x, b1.y, b1.z, b1.w};
            const float b2a[4] = {b2.x, b2.y, b2.z, b2.w};
            #pragma unroll
            for (int i = 0; i < 4; ++i)
                #pragma unroll
                for (int j = 0; j < 4; ++j) {
                    acc1[i][j] = fmaf(a1a[i], b1a[j], acc1[i][j]);
                    acc2[i][j] = fmaf(a2a[i], b2a[j], acc2[i][j]);
                }
        }
    }

    const float beta = beta_p[0];
    const float omb = 1.f - beta;
    #pragma unroll
    for (int i = 0; i < 4; ++i) {
        const int r = row0 + ty * 4 + i;
        if (r >= M) continue;
        #pragma unroll
        for (int j = 0; j < 4; ++j) {
            const int c = col0 + tx * 4 + j;
            float c1 = acc1[i][j] + linb[c];
            c1 = fmaxf(c1, 0.f);
            enc2[(size_t)r * Hn + c] = omb * c1 + beta * acc2[i][j];
        }
    }
}

__global__ __launch_bounds__(256) void cls_kernel_f32(
    const float* __restrict__ enc2, const float* __restrict__ clsW,
    const float* __restrict__ clsb, float* __restrict__ out, int B)
{
    const int wave = threadIdx.x >> 6;
    const int lane = threadIdx.x & 63;
    const int b = blockIdx.x * 4 + wave;
    if (b >= B) return;

    const float4 e = reinterpret_cast<const float4*>(enc2 + (size_t)b * Hn)[lane];
    const float4* __restrict__ clsWv = reinterpret_cast<const float4*>(clsW);

    float mylogit = -INFINITY;
    #pragma unroll
    for (int c0 = 0; c0 < Cn; c0 += 8) {
        float p[8];
        #pragma unroll
        for (int u = 0; u < 8; ++u) {
            const float4 wv = clsWv[(size_t)(c0 + u) * (Hn / 4) + lane];
            p[u] = e.x * wv.x + e.y * wv.y + e.z * wv.z + e.w * wv.w;
        }
        #pragma unroll
        for (int off = 32; off; off >>= 1) {
            #pragma unroll
            for (int u = 0; u < 8; ++u) p[u] += __shfl_xor(p[u], off);
        }
        #pragma unroll
        for (int u = 0; u < 8; ++u)
            if (lane == c0 + u) mylogit = p[u];
    }
    if (lane < Cn) mylogit += clsb[lane];

    float mx = mylogit;
    #pragma unroll
    for (int off = 32; off; off >>= 1) mx = fmaxf(mx, __shfl_xor(mx, off));
    float ex = (lane < Cn) ? expf(mylogit - mx) : 0.f;
    float se = ex;
    #pragma unroll
    for (int off = 32; off; off >>= 1) se += __shfl_xor(se, off);
    const float lse = logf(se);

    if (lane < Cn) out[(size_t)b * Cn + lane] = mylogit - mx - lse;
}

// ---------------------------------------------------------------------------
extern "C" void kernel_launch(void* const* d_in, const int* in_sizes, int n_in,
                              void* d_out, int out_size, void* d_ws, size_t ws_size,
                              hipStream_t stream) {
    const int*   nodes     = (const int*)d_in[0];
    const int*   structure = (const int*)d_in[1];
    const float* X         = (const float*)d_in[2];
    const float* beta      = (const float*)d_in[3];
    const float* waw       = (const float*)d_in[4];
    const float* wab       = (const float*)d_in[5];
    const float* linW      = (const float*)d_in[6];
    const float* linb      = (const float*)d_in[7];
    const float* skipW     = (const float*)d_in[8];
    const float* clsW      = (const float*)d_in[9];
    const float* clsb      = (const float*)d_in[10];
    float* out = (float*)d_out;

    const int B = in_sizes[0];
    const int Ntot = in_sizes[2];            // N * D floats

    // ws layout (bf16 path):
    //   h_bf   [B,D]   bf16
    //   selfb  [B,D]   bf16
    //   Xb     [N,D]   bf16
    //   linWp  [H,D]   bf16 fragment-packed
    //   skipWp [H,D]   bf16 fragment-packed
    //   clsWp  [48,H]  bf16 fragment-packed (zero-padded)
    unsigned short* h_bf   = (unsigned short*)d_ws;
    unsigned short* selfb  = h_bf + (size_t)B * Dn;
    unsigned short* Xb     = selfb + (size_t)B * Dn;
    unsigned short* linWp  = Xb + (size_t)Ntot;
    unsigned short* skipWp = linWp + (size_t)Hn * Dn;
    unsigned short* clsWp  = skipWp + (size_t)Hn * Dn;

    const size_t need = ((size_t)B * Dn * 2 + (size_t)Ntot +
                         (size_t)Hn * Dn * 2 + (size_t)CnP * Hn) * 2;

    if (ws_size >= need) {
        // Stage 0: one merged bf16 conversion launch (weights fragment-packed)
        const int x8 = Ntot / 8;
        const int w8 = (Hn * Dn) / 8;
        const int c8 = (CnP * Hn) / 8;
        const int G = x8 + 2 * w8 + c8;
        conv_all<<<(G + 255) / 256, 256, 0, stream>>>(
            X, linW, skipW, clsW,
            (uint4*)Xb, (uint4*)linWp, (uint4*)skipWp, (uint4*)clsWp, x8, w8);

        // Stage 1: message passing (bf16 gathers) -> h_bf, selfb
        mp_kernel_bf<<<(B + 3) / 4, 256, 0, stream>>>(
            nodes, structure, (const uint2*)Xb, waw, wab,
            (uint2*)h_bf, (uint2*)selfb, B);

        // Stage 2+3: fused dual-GEMM + classifier, coalesced fragments
        enc_cls16<<<(B + 15) / 16, 256, 0, stream>>>(
            h_bf, selfb, (const uint4*)linWp, linb, (const uint4*)skipWp,
            beta, (const uint4*)clsWp, clsb, out, B);
    } else {
        float* enc2 = (float*)d_ws;
        float* hf   = enc2 + (size_t)B * Hn;
        mp_kernel_f32<<<(B + 3) / 4, 256, 0, stream>>>(nodes, structure, X, waw, wab, hf, B);
        dim3 g2((B + BM - 1) / BM, Hn / BN);
        enc_gemm_f32<<<g2, 256, 0, stream>>>(hf, nodes, X, linW, linb, skipW, beta, enc2, B);
        cls_kernel_f32<<<(B + 3) / 4, 256, 0, stream>>>(enc2, clsW, clsb, out, B);
    }
}

// Round 15
// 120.636 us; speedup vs baseline: 1.3914x; 1.0672x over previous
//
#include <hip/hip_runtime.h>
#include <hip/hip_bf16.h>
#include <math.h>

// Problem constants (from reference)
#define Dn 256     // feature dim
#define En 16      // hyperedges per node
#define Kn 3       // nodes per hyperedge
#define Hn 256     // hidden dim
#define Cn 40      // classes
#define CnP 48     // classes padded to 3x16 for MFMA col tiles

typedef __attribute__((ext_vector_type(8)))  short bf16x8;
typedef __attribute__((ext_vector_type(4)))  float f32x4;

static __device__ __forceinline__ float bf2f(unsigned short u) {
    return __uint_as_float(((unsigned)u) << 16);
}
static __device__ __forceinline__ unsigned short f2bfbits(float v) {
    __hip_bfloat16 hb = __float2bfloat16(v);
    return *reinterpret_cast<unsigned short*>(&hb);
}
static __device__ __forceinline__ unsigned pack2bf(float a, float b) {
    return (unsigned)f2bfbits(a) | ((unsigned)f2bfbits(b) << 16);
}
// 5-bit LDS swizzle for 32x512B tiles: XOR row (bits 9..13) into the 16B-slot
// index (bits 4..8). 16-32 distinct rows at a fixed slot-column -> distinct
// slots -> conflict-free ds_read_b128.
static __device__ __forceinline__ unsigned swz5(unsigned boff) {
    return boff ^ (((boff >> 9) & 31u) << 4);
}

// ---------------------------------------------------------------------------
// Stage 0: merged fp32 -> bf16 conversion. X stays row-major; lin_W, skip_W,
// cls_W (zero-padded to 48 rows) are packed into MFMA-FRAGMENT ORDER:
//   packed[((ct*8 + kt)*64 + kg*16 + lc)] = 16B fragment (8 bf16) for
//   col = ct*16 + lc, k = kt*32 + kg*8 .. +7
// so a wave's B-fragment load is lane-consecutive (fully coalesced 1KB).
// ---------------------------------------------------------------------------
__global__ __launch_bounds__(256) void conv_all(
    const float* __restrict__ X, const float* __restrict__ linW,
    const float* __restrict__ skipW, const float* __restrict__ clsW,
    uint4* __restrict__ Xb, uint4* __restrict__ linWp,
    uint4* __restrict__ skipWp, uint4* __restrict__ clsWp,
    int x8, int w8)
{
    int t = blockIdx.x * 256 + threadIdx.x;
    const int c8 = (CnP * Hn) / 8;   // 1536 fragments for cls (48x256)
    if (t < x8) {
        const float4* iv = reinterpret_cast<const float4*>(X);
        const float4 a = iv[(size_t)t * 2 + 0];
        const float4 b = iv[(size_t)t * 2 + 1];
        Xb[t] = (uint4){pack2bf(a.x, a.y), pack2bf(a.z, a.w),
                        pack2bf(b.x, b.y), pack2bf(b.z, b.w)};
        return;
    }
    t -= x8;
    if (t < w8) {
        const float4* iv = reinterpret_cast<const float4*>(linW);
        const float4 a = iv[(size_t)t * 2 + 0];
        const float4 b = iv[(size_t)t * 2 + 1];
        const int lc = (t >> 5) & 15, ct = t >> 9;
        const int kt = (t >> 2) & 7,  kg = t & 3;
        linWp[(ct * 8 + kt) * 64 + kg * 16 + lc] =
            (uint4){pack2bf(a.x, a.y), pack2bf(a.z, a.w),
                    pack2bf(b.x, b.y), pack2bf(b.z, b.w)};
        return;
    }
    t -= w8;
    if (t < w8) {
        const float4* iv = reinterpret_cast<const float4*>(skipW);
        const float4 a = iv[(size_t)t * 2 + 0];
        const float4 b = iv[(size_t)t * 2 + 1];
        const int lc = (t >> 5) & 15, ct = t >> 9;
        const int kt = (t >> 2) & 7,  kg = t & 3;
        skipWp[(ct * 8 + kt) * 64 + kg * 16 + lc] =
            (uint4){pack2bf(a.x, a.y), pack2bf(a.z, a.w),
                    pack2bf(b.x, b.y), pack2bf(b.z, b.w)};
        return;
    }
    t -= w8;
    if (t < c8) {
        const int col = t >> 5;
        const int lc = col & 15, ct = t >> 9;
        const int kt = (t >> 2) & 7, kg = t & 3;
        const int dst = (ct * 8 + kt) * 64 + kg * 16 + lc;
        if (col < Cn) {
            const float4* iv = reinterpret_cast<const float4*>(clsW);
            const float4 a = iv[(size_t)t * 2 + 0];
            const float4 b = iv[(size_t)t * 2 + 1];
            clsWp[dst] = (uint4){pack2bf(a.x, a.y), pack2bf(a.z, a.w),
                                 pack2bf(b.x, b.y), pack2bf(b.z, b.w)};
        } else {
            clsWp[dst] = (uint4){0u, 0u, 0u, 0u};
        }
    }
}

// ---------------------------------------------------------------------------
// Stage 1 (bf16): message passing. One wave per node b (5000 blocks x 4
// waves -> proven 3.2-3.6 TB/s gather rate). Variance via S2-C identity.
// Streams self row out contiguously for the GEMM.
// ---------------------------------------------------------------------------
__global__ __launch_bounds__(256) void mp_kernel_bf(
    const int* __restrict__ nodes, const int* __restrict__ structure,
    const uint2* __restrict__ Xb,
    const float* __restrict__ waw_p, const float* __restrict__ wab_p,
    uint2* __restrict__ h_out, uint2* __restrict__ self_out, int B)
{
    const int wave = threadIdx.x >> 6;
    const int lane = threadIdx.x & 63;
    const int b = blockIdx.x * 4 + wave;
    if (b >= B) return;
    const int ub = __builtin_amdgcn_readfirstlane(b);  // wave-uniform

    const float waw = waw_p[0];
    const float wab = wab_p[0];

    float4 neigh = make_float4(0.f, 0.f, 0.f, 0.f);
    const int* st = structure + (size_t)ub * (En * Kn);

    #pragma unroll 1
    for (int g = 0; g < En / 4; ++g) {
        int idx[12];
        #pragma unroll
        for (int u = 0; u < 12; ++u) idx[u] = st[g * 12 + u];

        uint2 r0[4], r1[4], r2[4];
        #pragma unroll
        for (int u = 0; u < 4; ++u) {
            r0[u] = Xb[(size_t)idx[u * 3 + 0] * (Dn / 4) + lane];
            r1[u] = Xb[(size_t)idx[u * 3 + 1] * (Dn / 4) + lane];
            r2[u] = Xb[(size_t)idx[u * 3 + 2] * (Dn / 4) + lane];
        }

        float pv[4];
        float4 msg[4];
        #pragma unroll
        for (int u = 0; u < 4; ++u) {
            float4 f0, f1, f2;
            f0.x = bf2f((unsigned short)(r0[u].x & 0xffff));
            f0.y = bf2f((unsigned short)(r0[u].x >> 16));
            f0.z = bf2f((unsigned short)(r0[u].y & 0xffff));
            f0.w = bf2f((unsigned short)(r0[u].y >> 16));
            f1.x = bf2f((unsigned short)(r1[u].x & 0xffff));
            f1.y = bf2f((unsigned short)(r1[u].x >> 16));
            f1.z = bf2f((unsigned short)(r1[u].y & 0xffff));
            f1.w = bf2f((unsigned short)(r1[u].y >> 16));
            f2.x = bf2f((unsigned short)(r2[u].x & 0xffff));
            f2.y = bf2f((unsigned short)(r2[u].x >> 16));
            f2.z = bf2f((unsigned short)(r2[u].y & 0xffff));
            f2.w = bf2f((unsigned short)(r2[u].y >> 16));

            float s2 = 0.f, cr = 0.f, tt;
            s2 = fmaf(f0.x, f0.x, s2); s2 = fmaf(f1.x, f1.x, s2); s2 = fmaf(f2.x, f2.x, s2);
            tt = f1.x + f2.x; cr = fmaf(f0.x, tt, cr); cr = fmaf(f1.x, f2.x, cr);
            s2 = fmaf(f0.y, f0.y, s2); s2 = fmaf(f1.y, f1.y, s2); s2 = fmaf(f2.y, f2.y, s2);
            tt = f1.y + f2.y; cr = fmaf(f0.y, tt, cr); cr = fmaf(f1.y, f2.y, cr);
            s2 = fmaf(f0.z, f0.z, s2); s2 = fmaf(f1.z, f1.z, s2); s2 = fmaf(f2.z, f2.z, s2);
            tt = f1.z + f2.z; cr = fmaf(f0.z, tt, cr); cr = fmaf(f1.z, f2.z, cr);
            s2 = fmaf(f0.w, f0.w, s2); s2 = fmaf(f1.w, f1.w, s2); s2 = fmaf(f2.w, f2.w, s2);
            tt = f1.w + f2.w; cr = fmaf(f0.w, tt, cr); cr = fmaf(f1.w, f2.w, cr);

            pv[u] = s2 - cr;
            msg[u].x = f0.x * f1.x;
            msg[u].y = f0.y * f1.y;
            msg[u].z = f0.z * f1.z;
            msg[u].w = f0.w * f1.w;
        }

        #pragma unroll
        for (int off = 32; off; off >>= 1) {
            #pragma unroll
            for (int u = 0; u < 4; ++u) pv[u] += __shfl_xor(pv[u], off);
        }

        #pragma unroll
        for (int u = 0; u < 4; ++u) {
            const float var_mean = pv[u] * (2.f / (9.f * (float)Dn));
            const float att = 1.f / (1.f + expf(-(waw * var_mean + wab)));
            neigh.x += att * msg[u].x;
            neigh.y += att * msg[u].y;
            neigh.z += att * msg[u].z;
            neigh.w += att * msg[u].w;
        }
    }

    const uint2 sv = Xb[(size_t)nodes[ub] * (Dn / 4) + lane];
    self_out[(size_t)b * (Dn / 4) + lane] = sv;
    const float sx = bf2f((unsigned short)(sv.x & 0xffff));
    const float sy = bf2f((unsigned short)(sv.x >> 16));
    const float sz = bf2f((unsigned short)(sv.y & 0xffff));
    const float sw = bf2f((unsigned short)(sv.y >> 16));
    uint2 o;
    o.x = pack2bf(sx + neigh.x, sy + neigh.y);
    o.y = pack2bf(sz + neigh.z, sw + neigh.w);
    h_out[(size_t)b * (Dn / 4) + lane] = o;
}

// ---------------------------------------------------------------------------
// Stage 2+3 FUSED v3: 32 rows/block (2 row-tiles per wave) -> weight L2
// traffic halved vs 16-row version; B-fragments reused over 2 row-tiles.
// All fragment loads coalesced (packed weights; LDS-staged A). LDS 32 KB:
// hlds/slds; enc output OVERWRITES hlds after the GEMM sync (no elds).
// (256,4): VGPR cap 128 (accs 64 + ~50 live -> no spill). Waves 0,1 run cls.
// ---------------------------------------------------------------------------
__global__ __launch_bounds__(256, 4) void enc_cls32(
    const unsigned short* __restrict__ hB,     // [M,256] bf16
    const unsigned short* __restrict__ selfB,  // [M,256] bf16
    const uint4* __restrict__ linWp, const float* __restrict__ linb,
    const uint4* __restrict__ skipWp, const float* __restrict__ beta_p,
    const uint4* __restrict__ clsWp,           // packed [3][8][64]
    const float* __restrict__ clsb,
    float* __restrict__ out, int M)
{
    __shared__ unsigned short hlds[32 * 256];  // 16 KB swizzled (h; later enc)
    __shared__ unsigned short slds[32 * 256];  // 16 KB swizzled

    const int w    = threadIdx.x >> 6;   // col panel 0..3
    const int l    = threadIdx.x & 63;
    const int lr16 = l & 15;
    const int kg   = l >> 4;             // 0..3
    const int row0 = blockIdx.x * 32;

    // ---- stage h/self 32 rows each, coalesced -> swizzled LDS ----
    #pragma unroll
    for (int it = 0; it < 4; ++it) {
        const int ch = it * 256 + threadIdx.x;    // 0..1023 (16B chunks)
        const int r  = ch >> 5;                   // 0..31
        const int c  = ch & 31;                   // 16B col within row
        int grow = row0 + r;
        grow = grow < M ? grow : (M - 1);
        const uint4 hv = *reinterpret_cast<const uint4*>(hB    + (size_t)grow * Dn + c * 8);
        const uint4 sv = *reinterpret_cast<const uint4*>(selfB + (size_t)grow * Dn + c * 8);
        const unsigned boff = swz5((unsigned)(r * 512 + c * 16));
        *reinterpret_cast<uint4*>(reinterpret_cast<char*>(hlds) + boff) = hv;
        *reinterpret_cast<uint4*>(reinterpret_cast<char*>(slds) + boff) = sv;
    }
    __syncthreads();

    f32x4 acc1[2][4], acc2[2][4];
    #pragma unroll
    for (int rt = 0; rt < 2; ++rt)
        #pragma unroll
        for (int n = 0; n < 4; ++n) {
            acc1[rt][n] = (f32x4){0.f, 0.f, 0.f, 0.f};
            acc2[rt][n] = (f32x4){0.f, 0.f, 0.f, 0.f};
        }

    #pragma unroll 2
    for (int k0 = 0; k0 < Dn; k0 += 32) {
        const int kt = k0 >> 5;
        bf16x8 a1[2], a2[2];
        #pragma unroll
        for (int rt = 0; rt < 2; ++rt) {
            const unsigned aoff = swz5((unsigned)((rt * 16 + lr16) * 512 + k0 * 2 + kg * 16));
            a1[rt] = *reinterpret_cast<const bf16x8*>(
                reinterpret_cast<const char*>(hlds) + aoff);
            a2[rt] = *reinterpret_cast<const bf16x8*>(
                reinterpret_cast<const char*>(slds) + aoff);
        }
        #pragma unroll
        for (int n = 0; n < 4; ++n) {
            const int fidx = ((w * 4 + n) * 8 + kt) * 64 + l;   // coalesced
            const bf16x8 b1 = *reinterpret_cast<const bf16x8*>(linWp  + fidx);
            const bf16x8 b2 = *reinterpret_cast<const bf16x8*>(skipWp + fidx);
            #pragma unroll
            for (int rt = 0; rt < 2; ++rt) {
                acc1[rt][n] = __builtin_amdgcn_mfma_f32_16x16x32_bf16(a1[rt], b1, acc1[rt][n], 0, 0, 0);
                acc2[rt][n] = __builtin_amdgcn_mfma_f32_16x16x32_bf16(a2[rt], b2, acc2[rt][n], 0, 0, 0);
            }
        }
    }
    __syncthreads();   // all GEMM reads of hlds done before enc overwrites it

    // epilogue: enc -> hlds (swizzled bf16)
    const float beta = beta_p[0];
    const float omb = 1.f - beta;
    #pragma unroll
    for (int rt = 0; rt < 2; ++rt) {
        #pragma unroll
        for (int n = 0; n < 4; ++n) {
            const int col = w * 64 + n * 16 + lr16;
            const float bias = linb[col];
            #pragma unroll
            for (int r = 0; r < 4; ++r) {
                const int rowl = rt * 16 + kg * 4 + r;     // 0..31
                const float c1 = fmaxf(acc1[rt][n][r] + bias, 0.f);
                const unsigned short v = f2bfbits(omb * c1 + beta * acc2[rt][n][r]);
                const unsigned boff = swz5((unsigned)(rowl * 512 + col * 2));
                *reinterpret_cast<unsigned short*>(
                    reinterpret_cast<char*>(hlds) + boff) = v;
            }
        }
    }
    __syncthreads();

    // cls phase: waves 0,1 each handle 16 rows (B from packed clsWp)
    if (w < 2) {
        f32x4 cacc[3];
        cacc[0] = (f32x4){0.f,0.f,0.f,0.f};
        cacc[1] = (f32x4){0.f,0.f,0.f,0.f};
        cacc[2] = (f32x4){0.f,0.f,0.f,0.f};

        #pragma unroll
        for (int k0 = 0; k0 < Hn; k0 += 32) {
            const int kt = k0 >> 5;
            const unsigned boff = swz5((unsigned)((w * 16 + lr16) * 512 + k0 * 2 + kg * 16));
            const bf16x8 a = *reinterpret_cast<const bf16x8*>(
                reinterpret_cast<const char*>(hlds) + boff);
            #pragma unroll
            for (int t = 0; t < 3; ++t) {
                const bf16x8 bb = *reinterpret_cast<const bf16x8*>(
                    clsWp + ((t * 8 + kt) * 64 + l));
                cacc[t] = __builtin_amdgcn_mfma_f32_16x16x32_bf16(a, bb, cacc[t], 0, 0, 0);
            }
        }

        float bias3[3];
        #pragma unroll
        for (int t = 0; t < 3; ++t) {
            const int cb = t * 16 + lr16;
            bias3[t] = (cb < Cn) ? clsb[cb] : -INFINITY;
        }

        #pragma unroll
        for (int r = 0; r < 4; ++r) {
            float lg0 = cacc[0][r] + bias3[0];
            float lg1 = cacc[1][r] + bias3[1];
            float lg2 = cacc[2][r] + bias3[2];
            float mx = fmaxf(fmaxf(lg0, lg1), lg2);
            #pragma unroll
            for (int off = 8; off; off >>= 1) mx = fmaxf(mx, __shfl_xor(mx, off));
            float se = expf(lg0 - mx) + expf(lg1 - mx) + expf(lg2 - mx);
            #pragma unroll
            for (int off = 8; off; off >>= 1) se += __shfl_xor(se, off);
            const float lse = logf(se);

            const int row = row0 + w * 16 + kg * 4 + r;
            if (row < M) {
                if (lr16 < 8) out[(size_t)row * Cn + 32 + lr16] = lg2 - mx - lse;
                out[(size_t)row * Cn + lr16]      = lg0 - mx - lse;
                out[(size_t)row * Cn + 16 + lr16] = lg1 - mx - lse;
            }
        }
    }
}

// ---------------------------------------------------------------------------
// fp32 fallback path (only if ws_size too small for bf16 copies)
// ---------------------------------------------------------------------------
__global__ __launch_bounds__(256) void mp_kernel_f32(
    const int* __restrict__ nodes, const int* __restrict__ structure,
    const float* __restrict__ X, const float* __restrict__ waw_p,
    const float* __restrict__ wab_p, float* __restrict__ h_out, int B)
{
    const int wave = threadIdx.x >> 6;
    const int lane = threadIdx.x & 63;
    const int b = blockIdx.x * 4 + wave;
    if (b >= B) return;
    const int ub = __builtin_amdgcn_readfirstlane(b);

    const float waw = waw_p[0];
    const float wab = wab_p[0];
    const float4* __restrict__ Xv = reinterpret_cast<const float4*>(X);

    float4 neigh = make_float4(0.f, 0.f, 0.f, 0.f);
    const int* st = structure + (size_t)ub * (En * Kn);

    #pragma unroll 1
    for (int e = 0; e < En; ++e) {
        const int i0 = st[e * 3 + 0];
        const int i1 = st[e * 3 + 1];
        const int i2 = st[e * 3 + 2];
        const float4 f0 = Xv[(size_t)i0 * (Dn / 4) + lane];
        const float4 f1 = Xv[(size_t)i1 * (Dn / 4) + lane];
        const float4 f2 = Xv[(size_t)i2 * (Dn / 4) + lane];
        float pv = 0.f;
        {
            float a, bb, c, m;
            a = f0.x; bb = f1.x; c = f2.x;
            m = (a + bb + c) * (1.f / 3.f);
            pv += (a * a + bb * bb + c * c) * (1.f / 3.f) - m * m;
            a = f0.y; bb = f1.y; c = f2.y;
            m = (a + bb + c) * (1.f / 3.f);
            pv += (a * a + bb * bb + c * c) * (1.f / 3.f) - m * m;
            a = f0.z; bb = f1.z; c = f2.z;
            m = (a + bb + c) * (1.f / 3.f);
            pv += (a * a + bb * bb + c * c) * (1.f / 3.f) - m * m;
            a = f0.w; bb = f1.w; c = f2.w;
            m = (a + bb + c) * (1.f / 3.f);
            pv += (a * a + bb * bb + c * c) * (1.f / 3.f) - m * m;
        }
        #pragma unroll
        for (int off = 32; off; off >>= 1) pv += __shfl_xor(pv, off);
        const float var_mean = pv * (1.f / (float)Dn);
        const float att = 1.f / (1.f + expf(-(waw * var_mean + wab)));
        neigh.x += att * f0.x * f1.x;
        neigh.y += att * f0.y * f1.y;
        neigh.z += att * f0.z * f1.z;
        neigh.w += att * f0.w * f1.w;
    }

    const float4 s = Xv[(size_t)nodes[ub] * (Dn / 4) + lane];
    float4 h;
    h.x = s.x + neigh.x; h.y = s.y + neigh.y;
    h.z = s.z + neigh.z; h.w = s.w + neigh.w;
    reinterpret_cast<float4*>(h_out)[(size_t)b * (Dn / 4) + lane] = h;
}

#define BM 64
#define BN 64
#define BKs 16
#define LDT 68

__global__ __launch_bounds__(256) void enc_gemm_f32(
    const float* __restrict__ hA, const int* __restrict__ nodes,
    const float* __restrict__ X,
    const float* __restrict__ linW, const float* __restrict__ linb,
    const float* __restrict__ skipW, const float* __restrict__ beta_p,
    float* __restrict__ enc2, int M)
{
    __shared__ float Ats1[BKs][LDT];
    __shared__ float Ats2[BKs][LDT];
    __shared__ float Bts1[BKs][LDT];
    __shared__ float Bts2[BKs][LDT];

    const int tid = threadIdx.x;
    const int tx = tid & 15;
    const int ty = tid >> 4;
    const int row0 = blockIdx.x * BM;
    const int col0 = blockIdx.y * BN;

    const int lr = tid >> 2;
    const int lc = tid & 3;

    const int arow = row0 + lr;
    const bool arow_ok = arow < M;
    const int self_row = arow_ok ? nodes[arow] : 0;

    float acc1[4][4] = {{0.f}}, acc2[4][4] = {{0.f}};

    for (int k0 = 0; k0 < Dn; k0 += BKs) {
        float4 a1v = make_float4(0.f, 0.f, 0.f, 0.f);
        float4 a2v = make_float4(0.f, 0.f, 0.f, 0.f);
        if (arow_ok) {
            a1v = *reinterpret_cast<const float4*>(hA + (size_t)arow * Dn + k0 + lc * 4);
            a2v = *reinterpret_cast<const float4*>(X + (size_t)self_row * Dn + k0 + lc * 4);
        }
        const float4 b1v = *reinterpret_cast<const float4*>(linW + (size_t)(col0 + lr) * Dn + k0 + lc * 4);
        const float4 b2v = *reinterpret_cast<const float4*>(skipW + (size_t)(col0 + lr) * Dn + k0 + lc * 4);

        __syncthreads();
        Ats1[lc * 4 + 0][lr] = a1v.x; Ats1[lc * 4 + 1][lr] = a1v.y;
        Ats1[lc * 4 + 2][lr] = a1v.z; Ats1[lc * 4 + 3][lr] = a1v.w;
        Ats2[lc * 4 + 0][lr] = a2v.x; Ats2[lc * 4 + 1][lr] = a2v.y;
        Ats2[lc * 4 + 2][lr] = a2v.z; Ats2[lc * 4 + 3][lr] = a2v.w;
        Bts1[lc * 4 + 0][lr] = b1v.x; Bts1[lc * 4 + 1][lr] = b1v.y;
        Bts1[lc * 4 + 2][lr] = b1v.z; Bts1[lc * 4 + 3][lr] = b1v.w;
        Bts2[lc * 4 + 0][lr] = b2v.x; Bts2[lc * 4 + 1][lr] = b2v.y;
        Bts2[lc * 4 + 2][lr] = b2v.z; Bts2[lc * 4 + 3][lr] = b2v.w;
        __syncthreads();

        #pragma unroll
        for (int kk = 0; kk < BKs; ++kk) {
            const float4 a1 = *reinterpret_cast<const float4*>(&Ats1[kk][ty * 4]);
            const float4 a2 = *reinterpret_cast<const float4*>(&Ats2[kk][ty * 4]);
            const float4 b1 = *reinterpret_cast<const float4*>(&Bts1[kk][tx * 4]);
            const float4 b2 = *reinterpret_cast<const float4*>(&Bts2[kk][tx * 4]);
            const float a1a[4] = {a1.x, a1.y, a1.z, a1.w};
            const float a2a[4] = {a2.x, a2.y, a2.z, a2.w};
            const float b1a[4] = {b1.x, b1.y, b1.z, b1.w};
            const float b2a[4] = {b2.x, b2.y, b2.z, b2.w};
            #pragma unroll
            for (int i = 0; i < 4; ++i)
                #pragma unroll
                for (int j = 0; j < 4; ++j) {
                    acc1[i][j] = fmaf(a1a[i], b1a[j], acc1[i][j]);
                    acc2[i][j] = fmaf(a2a[i], b2a[j], acc2[i][j]);
                }
        }
    }

    const float beta = beta_p[0];
    const float omb = 1.f - beta;
    #pragma unroll
    for (int i = 0; i < 4; ++i) {
        const int r = row0 + ty * 4 + i;
        if (r >= M) continue;
        #pragma unroll
        for (int j = 0; j < 4; ++j) {
            const int c = col0 + tx * 4 + j;
            float c1 = acc1[i][j] + linb[c];
            c1 = fmaxf(c1, 0.f);
            enc2[(size_t)r * Hn + c] = omb * c1 + beta * acc2[i][j];
        }
    }
}

__global__ __launch_bounds__(256) void cls_kernel_f32(
    const float* __restrict__ enc2, const float* __restrict__ clsW,
    const float* __restrict__ clsb, float* __restrict__ out, int B)
{
    const int wave = threadIdx.x >> 6;
    const int lane = threadIdx.x & 63;
    const int b = blockIdx.x * 4 + wave;
    if (b >= B) return;

    const float4 e = reinterpret_cast<const float4*>(enc2 + (size_t)b * Hn)[lane];
    const float4* __restrict__ clsWv = reinterpret_cast<const float4*>(clsW);

    float mylogit = -INFINITY;
    #pragma unroll
    for (int c0 = 0; c0 < Cn; c0 += 8) {
        float p[8];
        #pragma unroll
        for (int u = 0; u < 8; ++u) {
            const float4 wv = clsWv[(size_t)(c0 + u) * (Hn / 4) + lane];
            p[u] = e.x * wv.x + e.y * wv.y + e.z * wv.z + e.w * wv.w;
        }
        #pragma unroll
        for (int off = 32; off; off >>= 1) {
            #pragma unroll
            for (int u = 0; u < 8; ++u) p[u] += __shfl_xor(p[u], off);
        }
        #pragma unroll
        for (int u = 0; u < 8; ++u)
            if (lane == c0 + u) mylogit = p[u];
    }
    if (lane < Cn) mylogit += clsb[lane];

    float mx = mylogit;
    #pragma unroll
    for (int off = 32; off; off >>= 1) mx = fmaxf(mx, __shfl_xor(mx, off));
    float ex = (lane < Cn) ? expf(mylogit - mx) : 0.f;
    float se = ex;
    #pragma unroll
    for (int off = 32; off; off >>= 1) se += __shfl_xor(se, off);
    const float lse = logf(se);

    if (lane < Cn) out[(size_t)b * Cn + lane] = mylogit - mx - lse;
}

// ---------------------------------------------------------------------------
extern "C" void kernel_launch(void* const* d_in, const int* in_sizes, int n_in,
                              void* d_out, int out_size, void* d_ws, size_t ws_size,
                              hipStream_t stream) {
    const int*   nodes     = (const int*)d_in[0];
    const int*   structure = (const int*)d_in[1];
    const float* X         = (const float*)d_in[2];
    const float* beta      = (const float*)d_in[3];
    const float* waw       = (const float*)d_in[4];
    const float* wab       = (const float*)d_in[5];
    const float* linW      = (const float*)d_in[6];
    const float* linb      = (const float*)d_in[7];
    const float* skipW     = (const float*)d_in[8];
    const float* clsW      = (const float*)d_in[9];
    const float* clsb      = (const float*)d_in[10];
    float* out = (float*)d_out;

    const int B = in_sizes[0];
    const int Ntot = in_sizes[2];            // N * D floats

    // ws layout (bf16 path):
    //   h_bf   [B,D]   bf16
    //   selfb  [B,D]   bf16
    //   Xb     [N,D]   bf16
    //   linWp  [H,D]   bf16 fragment-packed
    //   skipWp [H,D]   bf16 fragment-packed
    //   clsWp  [48,H]  bf16 fragment-packed (zero-padded)
    unsigned short* h_bf   = (unsigned short*)d_ws;
    unsigned short* selfb  = h_bf + (size_t)B * Dn;
    unsigned short* Xb     = selfb + (size_t)B * Dn;
    unsigned short* linWp  = Xb + (size_t)Ntot;
    unsigned short* skipWp = linWp + (size_t)Hn * Dn;
    unsigned short* clsWp  = skipWp + (size_t)Hn * Dn;

    const size_t need = ((size_t)B * Dn * 2 + (size_t)Ntot +
                         (size_t)Hn * Dn * 2 + (size_t)CnP * Hn) * 2;

    if (ws_size >= need) {
        // Stage 0: one merged bf16 conversion launch (weights fragment-packed)
        const int x8 = Ntot / 8;
        const int w8 = (Hn * Dn) / 8;
        const int c8 = (CnP * Hn) / 8;
        const int G = x8 + 2 * w8 + c8;
        conv_all<<<(G + 255) / 256, 256, 0, stream>>>(
            X, linW, skipW, clsW,
            (uint4*)Xb, (uint4*)linWp, (uint4*)skipWp, (uint4*)clsWp, x8, w8);

        // Stage 1: message passing (bf16 gathers) -> h_bf, selfb
        mp_kernel_bf<<<(B + 3) / 4, 256, 0, stream>>>(
            nodes, structure, (const uint2*)Xb, waw, wab,
            (uint2*)h_bf, (uint2*)selfb, B);

        // Stage 2+3: fused dual-GEMM + classifier, 32 rows/block
        enc_cls32<<<(B + 31) / 32, 256, 0, stream>>>(
            h_bf, selfb, (const uint4*)linWp, linb, (const uint4*)skipWp,
            beta, (const uint4*)clsWp, clsb, out, B);
    } else {
        float* enc2 = (float*)d_ws;
        float* hf   = enc2 + (size_t)B * Hn;
        mp_kernel_f32<<<(B + 3) / 4, 256, 0, stream>>>(nodes, structure, X, waw, wab, hf, B);
        dim3 g2((B + BM - 1) / BM, Hn / BN);
        enc_gemm_f32<<<g2, 256, 0, stream>>>(hf, nodes, X, linW, linb, skipW, beta, enc2, B);
        cls_kernel_f32<<<(B + 3) / 4, 256, 0, stream>>>(enc2, clsW, clsb, out, B);
    }
}

// Round 17
// 118.891 us; speedup vs baseline: 1.4119x; 1.0147x over previous
//
#include <hip/hip_runtime.h>
#include <hip/hip_bf16.h>
#include <math.h>

// Problem constants (from reference)
#define Dn 256     // feature dim
#define En 16      // hyperedges per node
#define Kn 3       // nodes per hyperedge
#define Hn 256     // hidden dim
#define Cn 40      // classes
#define CnP 48     // classes padded to 3x16 for MFMA col tiles

typedef __attribute__((ext_vector_type(8)))  short bf16x8;
typedef __attribute__((ext_vector_type(4)))  float f32x4;

static __device__ __forceinline__ float bf2f(unsigned short u) {
    return __uint_as_float(((unsigned)u) << 16);
}
static __device__ __forceinline__ unsigned short f2bfbits(float v) {
    __hip_bfloat16 hb = __float2bfloat16(v);
    return *reinterpret_cast<unsigned short*>(&hb);
}
static __device__ __forceinline__ unsigned pack2bf(float a, float b) {
    return (unsigned)f2bfbits(a) | ((unsigned)f2bfbits(b) << 16);
}
// fp8 e4m3 encode/decode. LAYOUT: sign@7, exp@6..3, mant@2..0.
// (round-16 bug: exp was at bits 7..4, colliding with the sign bit ->
// negative values decoded ~256x too large.)
static __device__ __forceinline__ unsigned enc_fp8(float x) {
    unsigned u = __float_as_uint(x);
    const unsigned s = u >> 31;
    unsigned a = u & 0x7fffffffu;
    if (a < 0x3c800000u) return s << 7;        // FTZ below 2^-6
    a += 0x7ffffu + ((a >> 20) & 1u);          // RTNE to 3-bit mantissa
    int e = (int)(a >> 23) - 120;              // e4m3 exponent (bias 7)
    unsigned m = (a >> 20) & 7u;
    if (e > 15) { e = 15; m = 7u; }            // saturate
    return (s << 7) | ((unsigned)e << 3) | m;
}
static __device__ __forceinline__ float dec_fp8(unsigned b) {
    const unsigned e = (b >> 3) & 15u;
    const unsigned f = ((b & 0x80u) << 24) | ((e + 120u) << 23) | ((b & 7u) << 20);
    return e ? __uint_as_float(f) : 0.f;       // encoder FTZ -> e==0 only zero
}
// 5-bit LDS swizzle for 32x512B tiles.
static __device__ __forceinline__ unsigned swz5(unsigned boff) {
    return boff ^ (((boff >> 9) & 31u) << 4);
}

// ---------------------------------------------------------------------------
// Stage 0: merged conversion. X -> bf16 row-major + fp8 row-major + per-row
// sum-of-squares sq[n] (32 consecutive threads own one 256-dim row -> 5-level
// shuffle reduce). lin_W/skip_W/cls_W packed into MFMA-fragment order.
// ---------------------------------------------------------------------------
__global__ __launch_bounds__(256) void conv_all(
    const float* __restrict__ X, const float* __restrict__ linW,
    const float* __restrict__ skipW, const float* __restrict__ clsW,
    uint4* __restrict__ Xb, uint4* __restrict__ linWp,
    uint4* __restrict__ skipWp, uint4* __restrict__ clsWp,
    uint2* __restrict__ X8, float* __restrict__ sq,
    int x8, int w8)
{
    int t = blockIdx.x * 256 + threadIdx.x;
    const int c8 = (CnP * Hn) / 8;   // 1536 fragments for cls (48x256)
    if (t < x8) {
        const float4* iv = reinterpret_cast<const float4*>(X);
        const float4 a = iv[(size_t)t * 2 + 0];
        const float4 b = iv[(size_t)t * 2 + 1];
        Xb[t] = (uint4){pack2bf(a.x, a.y), pack2bf(a.z, a.w),
                        pack2bf(b.x, b.y), pack2bf(b.z, b.w)};
        if (X8) {
            uint2 q;
            q.x = enc_fp8(a.x) | (enc_fp8(a.y) << 8) |
                  (enc_fp8(a.z) << 16) | (enc_fp8(a.w) << 24);
            q.y = enc_fp8(b.x) | (enc_fp8(b.y) << 8) |
                  (enc_fp8(b.z) << 16) | (enc_fp8(b.w) << 24);
            X8[t] = q;
        }
        // per-row sum of squares (32 threads per row)
        float p = a.x*a.x + a.y*a.y + a.z*a.z + a.w*a.w +
                  b.x*b.x + b.y*b.y + b.z*b.z + b.w*b.w;
        #pragma unroll
        for (int off = 16; off; off >>= 1) p += __shfl_xor(p, off);
        if ((threadIdx.x & 31) == 0) sq[t >> 5] = p;
        return;
    }
    t -= x8;
    if (t < w8) {
        const float4* iv = reinterpret_cast<const float4*>(linW);
        const float4 a = iv[(size_t)t * 2 + 0];
        const float4 b = iv[(size_t)t * 2 + 1];
        const int lc = (t >> 5) & 15, ct = t >> 9;
        const int kt = (t >> 2) & 7,  kg = t & 3;
        linWp[(ct * 8 + kt) * 64 + kg * 16 + lc] =
            (uint4){pack2bf(a.x, a.y), pack2bf(a.z, a.w),
                    pack2bf(b.x, b.y), pack2bf(b.z, b.w)};
        return;
    }
    t -= w8;
    if (t < w8) {
        const float4* iv = reinterpret_cast<const float4*>(skipW);
        const float4 a = iv[(size_t)t * 2 + 0];
        const float4 b = iv[(size_t)t * 2 + 1];
        const int lc = (t >> 5) & 15, ct = t >> 9;
        const int kt = (t >> 2) & 7,  kg = t & 3;
        skipWp[(ct * 8 + kt) * 64 + kg * 16 + lc] =
            (uint4){pack2bf(a.x, a.y), pack2bf(a.z, a.w),
                    pack2bf(b.x, b.y), pack2bf(b.z, b.w)};
        return;
    }
    t -= w8;
    if (t < c8) {
        const int col = t >> 5;
        const int lc = col & 15, ct = t >> 9;
        const int kt = (t >> 2) & 7, kg = t & 3;
        const int dst = (ct * 8 + kt) * 64 + kg * 16 + lc;
        if (col < Cn) {
            const float4* iv = reinterpret_cast<const float4*>(clsW);
            const float4 a = iv[(size_t)t * 2 + 0];
            const float4 b = iv[(size_t)t * 2 + 1];
            clsWp[dst] = (uint4){pack2bf(a.x, a.y), pack2bf(a.z, a.w),
                                 pack2bf(b.x, b.y), pack2bf(b.z, b.w)};
        } else {
            clsWp[dst] = (uint4){0u, 0u, 0u, 0u};
        }
    }
}

// ---------------------------------------------------------------------------
// Stage 1: message passing, variance via precomputed row norms:
//   sum_d var_d = (2/9)*(S2 - C), S2 = sq[i0]+sq[i1]+sq[i2] (scalar),
//   C = dot(f0,f1) + dot(f0+f1, f2).
// msg uses only f0,f1 (bf16). f2 feeds ONLY the dot -> gathered in fp8
// when available (USE_FP8), else bf16. One wave per node b.
// ---------------------------------------------------------------------------
template <bool USE_FP8>
__global__ __launch_bounds__(256) void mp_kernel_bf(
    const int* __restrict__ nodes, const int* __restrict__ structure,
    const uint2* __restrict__ Xb, const unsigned* __restrict__ X8,
    const float* __restrict__ sq,
    const float* __restrict__ waw_p, const float* __restrict__ wab_p,
    uint2* __restrict__ h_out, uint2* __restrict__ self_out, int B)
{
    const int wave = threadIdx.x >> 6;
    const int lane = threadIdx.x & 63;
    const int b = blockIdx.x * 4 + wave;
    if (b >= B) return;
    const int ub = __builtin_amdgcn_readfirstlane(b);  // wave-uniform

    const float waw = waw_p[0];
    const float wab = wab_p[0];

    float4 neigh = make_float4(0.f, 0.f, 0.f, 0.f);
    const int* st = structure + (size_t)ub * (En * Kn);

    #pragma unroll 1
    for (int g = 0; g < En / 4; ++g) {
        int idx[12];
        #pragma unroll
        for (int u = 0; u < 12; ++u) idx[u] = st[g * 12 + u];

        uint2 r0[4], r1[4], r2[4];
        unsigned q2[4];
        #pragma unroll
        for (int u = 0; u < 4; ++u) {
            r0[u] = Xb[(size_t)idx[u * 3 + 0] * (Dn / 4) + lane];
            r1[u] = Xb[(size_t)idx[u * 3 + 1] * (Dn / 4) + lane];
            if (USE_FP8) q2[u] = X8[(size_t)idx[u * 3 + 2] * (Dn / 4) + lane];
            else         r2[u] = Xb[(size_t)idx[u * 3 + 2] * (Dn / 4) + lane];
        }

        float pv[4];     // per-lane partial of C
        float4 msg[4];
        #pragma unroll
        for (int u = 0; u < 4; ++u) {
            float4 f0, f1;
            f0.x = bf2f((unsigned short)(r0[u].x & 0xffff));
            f0.y = bf2f((unsigned short)(r0[u].x >> 16));
            f0.z = bf2f((unsigned short)(r0[u].y & 0xffff));
            f0.w = bf2f((unsigned short)(r0[u].y >> 16));
            f1.x = bf2f((unsigned short)(r1[u].x & 0xffff));
            f1.y = bf2f((unsigned short)(r1[u].x >> 16));
            f1.z = bf2f((unsigned short)(r1[u].y & 0xffff));
            f1.w = bf2f((unsigned short)(r1[u].y >> 16));

            float g0, g1, g2, g3;
            if (USE_FP8) {
                const unsigned q = q2[u];
                g0 = dec_fp8(q & 0xffu);
                g1 = dec_fp8((q >> 8) & 0xffu);
                g2 = dec_fp8((q >> 16) & 0xffu);
                g3 = dec_fp8(q >> 24);
            } else {
                g0 = bf2f((unsigned short)(r2[u].x & 0xffff));
                g1 = bf2f((unsigned short)(r2[u].x >> 16));
                g2 = bf2f((unsigned short)(r2[u].y & 0xffff));
                g3 = bf2f((unsigned short)(r2[u].y >> 16));
            }

            msg[u].x = f0.x * f1.x;
            msg[u].y = f0.y * f1.y;
            msg[u].z = f0.z * f1.z;
            msg[u].w = f0.w * f1.w;

            float cp = msg[u].x + msg[u].y + msg[u].z + msg[u].w;
            cp = fmaf(f0.x + f1.x, g0, cp);
            cp = fmaf(f0.y + f1.y, g1, cp);
            cp = fmaf(f0.z + f1.z, g2, cp);
            cp = fmaf(f0.w + f1.w, g3, cp);
            pv[u] = cp;
        }

        #pragma unroll
        for (int off = 32; off; off >>= 1) {
            #pragma unroll
            for (int u = 0; u < 4; ++u) pv[u] += __shfl_xor(pv[u], off);
        }

        #pragma unroll
        for (int u = 0; u < 4; ++u) {
            const float S2 = sq[idx[u * 3 + 0]] + sq[idx[u * 3 + 1]] + sq[idx[u * 3 + 2]];
            const float var_mean = (S2 - pv[u]) * (2.f / (9.f * (float)Dn));
            const float att = 1.f / (1.f + expf(-(waw * var_mean + wab)));
            neigh.x += att * msg[u].x;
            neigh.y += att * msg[u].y;
            neigh.z += att * msg[u].z;
            neigh.w += att * msg[u].w;
        }
    }

    const uint2 sv = Xb[(size_t)nodes[ub] * (Dn / 4) + lane];
    self_out[(size_t)b * (Dn / 4) + lane] = sv;
    const float sx = bf2f((unsigned short)(sv.x & 0xffff));
    const float sy = bf2f((unsigned short)(sv.x >> 16));
    const float sz = bf2f((unsigned short)(sv.y & 0xffff));
    const float sw = bf2f((unsigned short)(sv.y >> 16));
    uint2 o;
    o.x = pack2bf(sx + neigh.x, sy + neigh.y);
    o.y = pack2bf(sz + neigh.z, sw + neigh.w);
    h_out[(size_t)b * (Dn / 4) + lane] = o;
}

// ---------------------------------------------------------------------------
// Stage 2+3 FUSED: 32 rows/block, 2 row-tiles/wave, coalesced fragments
// (packed weights; LDS-staged A). enc overwrites hlds. Waves 0,1 run cls.
// ---------------------------------------------------------------------------
__global__ __launch_bounds__(256, 4) void enc_cls32(
    const unsigned short* __restrict__ hB,     // [M,256] bf16
    const unsigned short* __restrict__ selfB,  // [M,256] bf16
    const uint4* __restrict__ linWp, const float* __restrict__ linb,
    const uint4* __restrict__ skipWp, const float* __restrict__ beta_p,
    const uint4* __restrict__ clsWp,           // packed [3][8][64]
    const float* __restrict__ clsb,
    float* __restrict__ out, int M)
{
    __shared__ unsigned short hlds[32 * 256];  // 16 KB swizzled (h; later enc)
    __shared__ unsigned short slds[32 * 256];  // 16 KB swizzled

    const int w    = threadIdx.x >> 6;   // col panel 0..3
    const int l    = threadIdx.x & 63;
    const int lr16 = l & 15;
    const int kg   = l >> 4;             // 0..3
    const int row0 = blockIdx.x * 32;

    // ---- stage h/self 32 rows each, coalesced -> swizzled LDS ----
    #pragma unroll
    for (int it = 0; it < 4; ++it) {
        const int ch = it * 256 + threadIdx.x;    // 0..1023 (16B chunks)
        const int r  = ch >> 5;                   // 0..31
        const int c  = ch & 31;                   // 16B col within row
        int grow = row0 + r;
        grow = grow < M ? grow : (M - 1);
        const uint4 hv = *reinterpret_cast<const uint4*>(hB    + (size_t)grow * Dn + c * 8);
        const uint4 sv = *reinterpret_cast<const uint4*>(selfB + (size_t)grow * Dn + c * 8);
        const unsigned boff = swz5((unsigned)(r * 512 + c * 16));
        *reinterpret_cast<uint4*>(reinterpret_cast<char*>(hlds) + boff) = hv;
        *reinterpret_cast<uint4*>(reinterpret_cast<char*>(slds) + boff) = sv;
    }
    __syncthreads();

    f32x4 acc1[2][4], acc2[2][4];
    #pragma unroll
    for (int rt = 0; rt < 2; ++rt)
        #pragma unroll
        for (int n = 0; n < 4; ++n) {
            acc1[rt][n] = (f32x4){0.f, 0.f, 0.f, 0.f};
            acc2[rt][n] = (f32x4){0.f, 0.f, 0.f, 0.f};
        }

    #pragma unroll 2
    for (int k0 = 0; k0 < Dn; k0 += 32) {
        const int kt = k0 >> 5;
        bf16x8 a1[2], a2[2];
        #pragma unroll
        for (int rt = 0; rt < 2; ++rt) {
            const unsigned aoff = swz5((unsigned)((rt * 16 + lr16) * 512 + k0 * 2 + kg * 16));
            a1[rt] = *reinterpret_cast<const bf16x8*>(
                reinterpret_cast<const char*>(hlds) + aoff);
            a2[rt] = *reinterpret_cast<const bf16x8*>(
                reinterpret_cast<const char*>(slds) + aoff);
        }
        #pragma unroll
        for (int n = 0; n < 4; ++n) {
            const int fidx = ((w * 4 + n) * 8 + kt) * 64 + l;   // coalesced
            const bf16x8 b1 = *reinterpret_cast<const bf16x8*>(linWp  + fidx);
            const bf16x8 b2 = *reinterpret_cast<const bf16x8*>(skipWp + fidx);
            #pragma unroll
            for (int rt = 0; rt < 2; ++rt) {
                acc1[rt][n] = __builtin_amdgcn_mfma_f32_16x16x32_bf16(a1[rt], b1, acc1[rt][n], 0, 0, 0);
                acc2[rt][n] = __builtin_amdgcn_mfma_f32_16x16x32_bf16(a2[rt], b2, acc2[rt][n], 0, 0, 0);
            }
        }
    }
    __syncthreads();   // all GEMM reads of hlds done before enc overwrites it

    // epilogue: enc -> hlds (swizzled bf16)
    const float beta = beta_p[0];
    const float omb = 1.f - beta;
    #pragma unroll
    for (int rt = 0; rt < 2; ++rt) {
        #pragma unroll
        for (int n = 0; n < 4; ++n) {
            const int col = w * 64 + n * 16 + lr16;
            const float bias = linb[col];
            #pragma unroll
            for (int r = 0; r < 4; ++r) {
                const int rowl = rt * 16 + kg * 4 + r;     // 0..31
                const float c1 = fmaxf(acc1[rt][n][r] + bias, 0.f);
                const unsigned short v = f2bfbits(omb * c1 + beta * acc2[rt][n][r]);
                const unsigned boff = swz5((unsigned)(rowl * 512 + col * 2));
                *reinterpret_cast<unsigned short*>(
                    reinterpret_cast<char*>(hlds) + boff) = v;
            }
        }
    }
    __syncthreads();

    // cls phase: waves 0,1 each handle 16 rows (B from packed clsWp)
    if (w < 2) {
        f32x4 cacc[3];
        cacc[0] = (f32x4){0.f,0.f,0.f,0.f};
        cacc[1] = (f32x4){0.f,0.f,0.f,0.f};
        cacc[2] = (f32x4){0.f,0.f,0.f,0.f};

        #pragma unroll
        for (int k0 = 0; k0 < Hn; k0 += 32) {
            const int kt = k0 >> 5;
            const unsigned boff = swz5((unsigned)((w * 16 + lr16) * 512 + k0 * 2 + kg * 16));
            const bf16x8 a = *reinterpret_cast<const bf16x8*>(
                reinterpret_cast<const char*>(hlds) + boff);
            #pragma unroll
            for (int t = 0; t < 3; ++t) {
                const bf16x8 bb = *reinterpret_cast<const bf16x8*>(
                    clsWp + ((t * 8 + kt) * 64 + l));
                cacc[t] = __builtin_amdgcn_mfma_f32_16x16x32_bf16(a, bb, cacc[t], 0, 0, 0);
            }
        }

        float bias3[3];
        #pragma unroll
        for (int t = 0; t < 3; ++t) {
            const int cb = t * 16 + lr16;
            bias3[t] = (cb < Cn) ? clsb[cb] : -INFINITY;
        }

        #pragma unroll
        for (int r = 0; r < 4; ++r) {
            float lg0 = cacc[0][r] + bias3[0];
            float lg1 = cacc[1][r] + bias3[1];
            float lg2 = cacc[2][r] + bias3[2];
            float mx = fmaxf(fmaxf(lg0, lg1), lg2);
            #pragma unroll
            for (int off = 8; off; off >>= 1) mx = fmaxf(mx, __shfl_xor(mx, off));
            float se = expf(lg0 - mx) + expf(lg1 - mx) + expf(lg2 - mx);
            #pragma unroll
            for (int off = 8; off; off >>= 1) se += __shfl_xor(se, off);
            const float lse = logf(se);

            const int row = row0 + w * 16 + kg * 4 + r;
            if (row < M) {
                if (lr16 < 8) out[(size_t)row * Cn + 32 + lr16] = lg2 - mx - lse;
                out[(size_t)row * Cn + lr16]      = lg0 - mx - lse;
                out[(size_t)row * Cn + 16 + lr16] = lg1 - mx - lse;
            }
        }
    }
}

// ---------------------------------------------------------------------------
// fp32 fallback path (only if ws_size too small for bf16 copies)
// ---------------------------------------------------------------------------
__global__ __launch_bounds__(256) void mp_kernel_f32(
    const int* __restrict__ nodes, const int* __restrict__ structure,
    const float* __restrict__ X, const float* __restrict__ waw_p,
    const float* __restrict__ wab_p, float* __restrict__ h_out, int B)
{
    const int wave = threadIdx.x >> 6;
    const int lane = threadIdx.x & 63;
    const int b = blockIdx.x * 4 + wave;
    if (b >= B) return;
    const int ub = __builtin_amdgcn_readfirstlane(b);

    const float waw = waw_p[0];
    const float wab = wab_p[0];
    const float4* __restrict__ Xv = reinterpret_cast<const float4*>(X);

    float4 neigh = make_float4(0.f, 0.f, 0.f, 0.f);
    const int* st = structure + (size_t)ub * (En * Kn);

    #pragma unroll 1
    for (int e = 0; e < En; ++e) {
        const int i0 = st[e * 3 + 0];
        const int i1 = st[e * 3 + 1];
        const int i2 = st[e * 3 + 2];
        const float4 f0 = Xv[(size_t)i0 * (Dn / 4) + lane];
        const float4 f1 = Xv[(size_t)i1 * (Dn / 4) + lane];
        const float4 f2 = Xv[(size_t)i2 * (Dn / 4) + lane];
        float pv = 0.f;
        {
            float a, bb, c, m;
            a = f0.x; bb = f1.x; c = f2.x;
            m = (a + bb + c) * (1.f / 3.f);
            pv += (a * a + bb * bb + c * c) * (1.f / 3.f) - m * m;
            a = f0.y; bb = f1.y; c = f2.y;
            m = (a + bb + c) * (1.f / 3.f);
            pv += (a * a + bb * bb + c * c) * (1.f / 3.f) - m * m;
            a = f0.z; bb = f1.z; c = f2.z;
            m = (a + bb + c) * (1.f / 3.f);
            pv += (a * a + bb * bb + c * c) * (1.f / 3.f) - m * m;
            a = f0.w; bb = f1.w; c = f2.w;
            m = (a + bb + c) * (1.f / 3.f);
            pv += (a * a + bb * bb + c * c) * (1.f / 3.f) - m * m;
        }
        #pragma unroll
        for (int off = 32; off; off >>= 1) pv += __shfl_xor(pv, off);
        const float var_mean = pv * (1.f / (float)Dn);
        const float att = 1.f / (1.f + expf(-(waw * var_mean + wab)));
        neigh.x += att * f0.x * f1.x;
        neigh.y += att * f0.y * f1.y;
        neigh.z += att * f0.z * f1.z;
        neigh.w += att * f0.w * f1.w;
    }

    const float4 s = Xv[(size_t)nodes[ub] * (Dn / 4) + lane];
    float4 h;
    h.x = s.x + neigh.x; h.y = s.y + neigh.y;
    h.z = s.z + neigh.z; h.w = s.w + neigh.w;
    reinterpret_cast<float4*>(h_out)[(size_t)b * (Dn / 4) + lane] = h;
}

#define BM 64
#define BN 64
#define BKs 16
#define LDT 68

__global__ __launch_bounds__(256) void enc_gemm_f32(
    const float* __restrict__ hA, const int* __restrict__ nodes,
    const float* __restrict__ X,
    const float* __restrict__ linW, const float* __restrict__ linb,
    const float* __restrict__ skipW, const float* __restrict__ beta_p,
    float* __restrict__ enc2, int M)
{
    __shared__ float Ats1[BKs][LDT];
    __shared__ float Ats2[BKs][LDT];
    __shared__ float Bts1[BKs][LDT];
    __shared__ float Bts2[BKs][LDT];

    const int tid = threadIdx.x;
    const int tx = tid & 15;
    const int ty = tid >> 4;
    const int row0 = blockIdx.x * BM;
    const int col0 = blockIdx.y * BN;

    const int lr = tid >> 2;
    const int lc = tid & 3;

    const int arow = row0 + lr;
    const bool arow_ok = arow < M;
    const int self_row = arow_ok ? nodes[arow] : 0;

    float acc1[4][4] = {{0.f}}, acc2[4][4] = {{0.f}};

    for (int k0 = 0; k0 < Dn; k0 += BKs) {
        float4 a1v = make_float4(0.f, 0.f, 0.f, 0.f);
        float4 a2v = make_float4(0.f, 0.f, 0.f, 0.f);
        if (arow_ok) {
            a1v = *reinterpret_cast<const float4*>(hA + (size_t)arow * Dn + k0 + lc * 4);
            a2v = *reinterpret_cast<const float4*>(X + (size_t)self_row * Dn + k0 + lc * 4);
        }
        const float4 b1v = *reinterpret_cast<const float4*>(linW + (size_t)(col0 + lr) * Dn + k0 + lc * 4);
        const float4 b2v = *reinterpret_cast<const float4*>(skipW + (size_t)(col0 + lr) * Dn + k0 + lc * 4);

        __syncthreads();
        Ats1[lc * 4 + 0][lr] = a1v.x; Ats1[lc * 4 + 1][lr] = a1v.y;
        Ats1[lc * 4 + 2][lr] = a1v.z; Ats1[lc * 4 + 3][lr] = a1v.w;
        Ats2[lc * 4 + 0][lr] = a2v.x; Ats2[lc * 4 + 1][lr] = a2v.y;
        Ats2[lc * 4 + 2][lr] = a2v.z; Ats2[lc * 4 + 3][lr] = a2v.w;
        Bts1[lc * 4 + 0][lr] = b1v.x; Bts1[lc * 4 + 1][lr] = b1v.y;
        Bts1[lc * 4 + 2][lr] = b1v.z; Bts1[lc * 4 + 3][lr] = b1v.w;
        Bts2[lc * 4 + 0][lr] = b2v.x; Bts2[lc * 4 + 1][lr] = b2v.y;
        Bts2[lc * 4 + 2][lr] = b2v.z; Bts2[lc * 4 + 3][lr] = b2v.w;
        __syncthreads();

        #pragma unroll
        for (int kk = 0; kk < BKs; ++kk) {
            const float4 a1 = *reinterpret_cast<const float4*>(&Ats1[kk][ty * 4]);
            const float4 a2 = *reinterpret_cast<const float4*>(&Ats2[kk][ty * 4]);
            const float4 b1 = *reinterpret_cast<const float4*>(&Bts1[kk][tx * 4]);
            const float4 b2 = *reinterpret_cast<const float4*>(&Bts2[kk][tx * 4]);
            const float a1a[4] = {a1.x, a1.y, a1.z, a1.w};
            const float a2a[4] = {a2.x, a2.y, a2.z, a2.w};
            const float b1a[4] = {b1.x, b1.y, b1.z, b1.w};
            const float b2a[4] = {b2.x, b2.y, b2.z, b2.w};
            #pragma unroll
            for (int i = 0; i < 4; ++i)
                #pragma unroll
                for (int j = 0; j < 4; ++j) {
                    acc1[i][j] = fmaf(a1a[i], b1a[j], acc1[i][j]);
                    acc2[i][j] = fmaf(a2a[i], b2a[j], acc2[i][j]);
                }
        }
    }

    const float beta = beta_p[0];
    const float omb = 1.f - beta;
    #pragma unroll
    for (int i = 0; i < 4; ++i) {
        const int r = row0 + ty * 4 + i;
        if (r >= M) continue;
        #pragma unroll
        for (int j = 0; j < 4; ++j) {
            const int c = col0 + tx * 4 + j;
            float c1 = acc1[i][j] + linb[c];
            c1 = fmaxf(c1, 0.f);
            enc2[(size_t)r * Hn + c] = omb * c1 + beta * acc2[i][j];
        }
    }
}

__global__ __launch_bounds__(256) void cls_kernel_f32(
    const float* __restrict__ enc2, const float* __restrict__ clsW,
    const float* __restrict__ clsb, float* __restrict__ out, int B)
{
    const int wave = threadIdx.x >> 6;
    const int lane = threadIdx.x & 63;
    const int b = blockIdx.x * 4 + wave;
    if (b >= B) return;

    const float4 e = reinterpret_cast<const float4*>(enc2 + (size_t)b * Hn)[lane];
    const float4* __restrict__ clsWv = reinterpret_cast<const float4*>(clsW);

    float mylogit = -INFINITY;
    #pragma unroll
    for (int c0 = 0; c0 < Cn; c0 += 8) {
        float p[8];
        #pragma unroll
        for (int u = 0; u < 8; ++u) {
            const float4 wv = clsWv[(size_t)(c0 + u) * (Hn / 4) + lane];
            p[u] = e.x * wv.x + e.y * wv.y + e.z * wv.z + e.w * wv.w;
        }
        #pragma unroll
        for (int off = 32; off; off >>= 1) {
            #pragma unroll
            for (int u = 0; u < 8; ++u) p[u] += __shfl_xor(p[u], off);
        }
        #pragma unroll
        for (int u = 0; u < 8; ++u)
            if (lane == c0 + u) mylogit = p[u];
    }
    if (lane < Cn) mylogit += clsb[lane];

    float mx = mylogit;
    #pragma unroll
    for (int off = 32; off; off >>= 1) mx = fmaxf(mx, __shfl_xor(mx, off));
    float ex = (lane < Cn) ? expf(mylogit - mx) : 0.f;
    float se = ex;
    #pragma unroll
    for (int off = 32; off; off >>= 1) se += __shfl_xor(se, off);
    const float lse = logf(se);

    if (lane < Cn) out[(size_t)b * Cn + lane] = mylogit - mx - lse;
}

// ---------------------------------------------------------------------------
extern "C" void kernel_launch(void* const* d_in, const int* in_sizes, int n_in,
                              void* d_out, int out_size, void* d_ws, size_t ws_size,
                              hipStream_t stream) {
    const int*   nodes     = (const int*)d_in[0];
    const int*   structure = (const int*)d_in[1];
    const float* X         = (const float*)d_in[2];
    const float* beta      = (const float*)d_in[3];
    const float* waw       = (const float*)d_in[4];
    const float* wab       = (const float*)d_in[5];
    const float* linW      = (const float*)d_in[6];
    const float* linb      = (const float*)d_in[7];
    const float* skipW     = (const float*)d_in[8];
    const float* clsW      = (const float*)d_in[9];
    const float* clsb      = (const float*)d_in[10];
    float* out = (float*)d_out;

    const int B = in_sizes[0];
    const int Ntot = in_sizes[2];            // N * D floats
    const int N = Ntot / Dn;

    // ws layout (prefix = bf16 tier; fp8 tier appends X8 + keeps sq):
    //   h_bf, selfb [B,D] bf16 ; Xb [N,D] bf16 ; linWp/skipWp [H,D] packed ;
    //   clsWp [48,H] packed ; sq [N] fp32 ; X8 [N,D] fp8 (fp8 tier only)
    unsigned short* h_bf   = (unsigned short*)d_ws;
    unsigned short* selfb  = h_bf + (size_t)B * Dn;
    unsigned short* Xb     = selfb + (size_t)B * Dn;
    unsigned short* linWp  = Xb + (size_t)Ntot;
    unsigned short* skipWp = linWp + (size_t)Hn * Dn;
    unsigned short* clsWp  = skipWp + (size_t)Hn * Dn;
    float*          sqp    = (float*)(clsWp + (size_t)CnP * Hn);
    unsigned char*  X8p    = (unsigned char*)(sqp + (size_t)N);

    const size_t need_bf16 = ((size_t)B * Dn * 2 + (size_t)Ntot +
                              (size_t)Hn * Dn * 2 + (size_t)CnP * Hn) * 2 +
                             (size_t)N * 4;
    const size_t need_fp8  = need_bf16 + (size_t)Ntot;

    if (ws_size >= need_bf16) {
        const bool fp8 = (ws_size >= need_fp8);

        // Stage 0: merged conversion
        const int x8 = Ntot / 8;
        const int w8 = (Hn * Dn) / 8;
        const int c8 = (CnP * Hn) / 8;
        const int G = x8 + 2 * w8 + c8;
        conv_all<<<(G + 255) / 256, 256, 0, stream>>>(
            X, linW, skipW, clsW,
            (uint4*)Xb, (uint4*)linWp, (uint4*)skipWp, (uint4*)clsWp,
            fp8 ? (uint2*)X8p : nullptr, sqp, x8, w8);

        // Stage 1: message passing -> h_bf, selfb
        if (fp8) {
            mp_kernel_bf<true><<<(B + 3) / 4, 256, 0, stream>>>(
                nodes, structure, (const uint2*)Xb, (const unsigned*)X8p, sqp,
                waw, wab, (uint2*)h_bf, (uint2*)selfb, B);
        } else {
            mp_kernel_bf<false><<<(B + 3) / 4, 256, 0, stream>>>(
                nodes, structure, (const uint2*)Xb, nullptr, sqp,
                waw, wab, (uint2*)h_bf, (uint2*)selfb, B);
        }

        // Stage 2+3: fused dual-GEMM + classifier, 32 rows/block
        enc_cls32<<<(B + 31) / 32, 256, 0, stream>>>(
            h_bf, selfb, (const uint4*)linWp, linb, (const uint4*)skipWp,
            beta, (const uint4*)clsWp, clsb, out, B);
    } else {
        float* enc2 = (float*)d_ws;
        float* hf   = enc2 + (size_t)B * Hn;
        mp_kernel_f32<<<(B + 3) / 4, 256, 0, stream>>>(nodes, structure, X, waw, wab, hf, B);
        dim3 g2((B + BM - 1) / BM, Hn / BN);
        enc_gemm_f32<<<g2, 256, 0, stream>>>(hf, nodes, X, linW, linb, skipW, beta, enc2, B);
        cls_kernel_f32<<<(B + 3) / 4, 256, 0, stream>>>(enc2, clsW, clsb, out, B);
    }
}